// Round 1
// baseline (829.915 us; speedup 1.0000x reference)
//
#include <hip/hip_runtime.h>

#define NN 50000
#define NE 800000
#define IND 64
#define HID 128
#define NG 1024

static __device__ __forceinline__ float4 f4zero() { return make_float4(0.f, 0.f, 0.f, 0.f); }

// ---------------- CSR build ----------------
__global__ void hist_kernel(const int* __restrict__ dst, int* __restrict__ cnt) {
    int i = blockIdx.x * 256 + threadIdx.x;
    if (i < NE) atomicAdd(&cnt[dst[i]], 1);
}

__global__ void scan_block_kernel(const int* __restrict__ in, int* __restrict__ out,
                                  int* __restrict__ bsums, int n) {
    __shared__ int s[256];
    int tid = threadIdx.x;
    int i = blockIdx.x * 256 + tid;
    int v = (i < n) ? in[i] : 0;
    s[tid] = v;
    __syncthreads();
    for (int off = 1; off < 256; off <<= 1) {
        int add = (tid >= off) ? s[tid - off] : 0;
        __syncthreads();
        s[tid] += add;
        __syncthreads();
    }
    if (i < n) out[i] = s[tid] - v;  // exclusive scan within block
    if (tid == 255) bsums[blockIdx.x] = s[255];
}

__global__ void scan_sums_kernel(int* __restrict__ bsums, int nb) {
    __shared__ int s[256];
    int tid = threadIdx.x;
    int v = (tid < nb) ? bsums[tid] : 0;
    s[tid] = v;
    __syncthreads();
    for (int off = 1; off < 256; off <<= 1) {
        int add = (tid >= off) ? s[tid - off] : 0;
        __syncthreads();
        s[tid] += add;
        __syncthreads();
    }
    if (tid < nb) bsums[tid] = s[tid] - v;  // exclusive
}

__global__ void scan_add_kernel(int* __restrict__ row_ptr, int* __restrict__ cursor,
                                const int* __restrict__ bsums, int n) {
    int i = blockIdx.x * 256 + threadIdx.x;
    if (i < n) {
        int v = row_ptr[i] + bsums[blockIdx.x];
        row_ptr[i] = v;
        cursor[i] = v;
    }
    if (blockIdx.x == 0 && threadIdx.x == 0) row_ptr[n] = NE;
}

__global__ void fill_csr_kernel(const int* __restrict__ src, const int* __restrict__ dst,
                                int* __restrict__ cursor, int* __restrict__ esrc) {
    int i = blockIdx.x * 256 + threadIdx.x;
    if (i < NE) {
        int p = atomicAdd(&cursor[dst[i]], 1);
        esrc[p] = src[i];
    }
}

// ---------------- aggregation: out[n] = x[n] + sum_{e in CSR row n} x[esrc[e]] ----------------
// one wave per node; lanes own columns (float2 for D=128, float for D=64)
template <int D>
__global__ void agg_kernel(const float* __restrict__ x, const int* __restrict__ row_ptr,
                           const int* __restrict__ esrc, float* __restrict__ out) {
    int wv = threadIdx.x >> 6, lane = threadIdx.x & 63;
    int n = blockIdx.x * 4 + wv;
    if (n >= NN) return;
    int beg = row_ptr[n], end = row_ptr[n + 1];
    if (D == 128) {
        const float2* xp = (const float2*)x;
        float2 acc = xp[(size_t)n * 64 + lane];
        for (int e = beg; e < end; ++e) {
            int s = esrc[e];
            float2 v = xp[(size_t)s * 64 + lane];
            acc.x += v.x;
            acc.y += v.y;
        }
        ((float2*)out)[(size_t)n * 64 + lane] = acc;
    } else {
        float acc = x[(size_t)n * 64 + lane];
        for (int e = beg; e < end; ++e) acc += x[(size_t)esrc[e] * 64 + lane];
        out[(size_t)n * 64 + lane] = acc;
    }
}

// ---------------- fused node-GEMM: out[N,128] = act(in[N,K] @ W[K,128] + b [+ res]) ----------------
// MODE 0: plain; MODE 1: relu(out); MODE 2: relu(out + res)
// 32-node tile, W staged in 64-row LDS chunks (48 KB LDS total -> 3 blocks/CU)
template <int K, int MODE>
__global__ __launch_bounds__(256, 3) void gemm_kernel(
    const float* __restrict__ in, const float* __restrict__ W,
    const float* __restrict__ bias, const float* __restrict__ res,
    float* __restrict__ out, int nRows) {
    __shared__ float sW[64 * 128];
    __shared__ float sIn[32 * K];
    int tid = threadIdx.x;
    int rowBase = blockIdx.x * 32;

    // stage input tile [32][K]
    for (int i = tid; i < 32 * K / 4; i += 256) {
        int r = i / (K / 4), c = i % (K / 4);
        int row = rowBase + r;
        float4 v = f4zero();
        if (row < nRows) v = ((const float4*)(in + (size_t)row * K))[c];
        ((float4*)sIn)[i] = v;
    }

    int c4 = tid & 31;  // column group: cols c4*4 .. c4*4+3
    int ng = tid >> 5;  // node group: nodes ng*4 .. ng*4+3
    float4 b = bias ? ((const float4*)bias)[c4] : f4zero();
    float4 acc[4] = {b, b, b, b};

    for (int kc = 0; kc < K; kc += 64) {
        __syncthreads();
        for (int i = tid; i < 64 * 128 / 4; i += 256)
            ((float4*)sW)[i] = ((const float4*)(W + (size_t)kc * 128))[i];
        __syncthreads();
#pragma unroll 8
        for (int k = 0; k < 64; ++k) {
            float4 w = ((const float4*)(sW + k * 128))[c4];
#pragma unroll
            for (int i = 0; i < 4; ++i) {
                float a = sIn[(ng * 4 + i) * K + kc + k];
                acc[i].x = fmaf(a, w.x, acc[i].x);
                acc[i].y = fmaf(a, w.y, acc[i].y);
                acc[i].z = fmaf(a, w.z, acc[i].z);
                acc[i].w = fmaf(a, w.w, acc[i].w);
            }
        }
    }

#pragma unroll
    for (int i = 0; i < 4; ++i) {
        int row = rowBase + ng * 4 + i;
        if (row >= nRows) continue;
        float4 v = acc[i];
        if (MODE == 2) {
            float4 r4 = ((const float4*)(res + (size_t)row * 128))[c4];
            v.x = fmaxf(v.x + r4.x, 0.f);
            v.y = fmaxf(v.y + r4.y, 0.f);
            v.z = fmaxf(v.z + r4.z, 0.f);
            v.w = fmaxf(v.w + r4.w, 0.f);
        } else if (MODE == 1) {
            v.x = fmaxf(v.x, 0.f);
            v.y = fmaxf(v.y, 0.f);
            v.z = fmaxf(v.z, 0.f);
            v.w = fmaxf(v.w, 0.f);
        }
        ((float4*)(out + (size_t)row * 128))[c4] = v;
    }
}

// ---------------- pooling + head ----------------
__global__ void pool_sum_kernel(const float* __restrict__ h, const int* __restrict__ batch,
                                float* __restrict__ gsum) {
    int idx = blockIdx.x * 256 + threadIdx.x;
    if (idx >= NN * 64) return;
    int n = idx >> 6, c = (idx & 63) * 2;
    int g = batch[n];
    float2 v = *(const float2*)(h + (size_t)n * 128 + c);
    atomicAdd(&gsum[g * 128 + c], v.x);
    atomicAdd(&gsum[g * 128 + c + 1], v.y);
}

__global__ void pool_cnt_kernel(const int* __restrict__ batch, int* __restrict__ gcnt) {
    int i = blockIdx.x * 256 + threadIdx.x;
    if (i < NN) atomicAdd(&gcnt[batch[i]], 1);
}

__global__ void head_kernel(const float* __restrict__ gsum, const int* __restrict__ gcnt,
                            const float* __restrict__ fW1, const float* __restrict__ fb1,
                            const float* __restrict__ fW2, const float* __restrict__ fb2,
                            float* __restrict__ out) {
    __shared__ float sp[128];
    __shared__ float su[128];
    int g = blockIdx.x, t = threadIdx.x;
    float cnt = (float)max(gcnt[g], 1);
    sp[t] = gsum[g * 128 + t] / cnt;
    __syncthreads();
    float a = fb1[t];
#pragma unroll 4
    for (int k = 0; k < 128; ++k) a = fmaf(sp[k], fW1[k * 128 + t], a);
    a = a > 0.f ? a : 0.01f * a;  // LeakyReLU(0.01)
    su[t] = a * fW2[t];
    __syncthreads();
    for (int s2 = 64; s2 > 0; s2 >>= 1) {
        if (t < s2) su[t] += su[t + s2];
        __syncthreads();
    }
    if (t == 0) out[g] = su[0] + fb2[0];
}

extern "C" void kernel_launch(void* const* d_in, const int* in_sizes, int n_in,
                              void* d_out, int out_size, void* d_ws, size_t ws_size,
                              hipStream_t stream) {
    const float* x = (const float*)d_in[0];
    const int* eidx = (const int*)d_in[1];
    const int* src = eidx;            // edge_index[0]
    const int* dst = eidx + NE;       // edge_index[1]
    const int* batch = (const int*)d_in[2];
    const float* l0_W1 = (const float*)d_in[3];
    const float* l0_b1 = (const float*)d_in[4];
    const float* l0_W2 = (const float*)d_in[5];
    const float* l0_b2 = (const float*)d_in[6];
    const float* l0_Wres = (const float*)d_in[7];
    const float* Ws1 = (const float*)d_in[8];
    const float* bs1 = (const float*)d_in[9];
    const float* Ws2 = (const float*)d_in[10];
    const float* bs2 = (const float*)d_in[11];
    const float* fW1 = (const float*)d_in[12];
    const float* fb1 = (const float*)d_in[13];
    const float* fW2 = (const float*)d_in[14];
    const float* fb2 = (const float*)d_in[15];
    float* out = (float*)d_out;

    char* p = (char*)d_ws;
    auto alloc = [&](size_t bytes) {
        char* r = p;
        p += (bytes + 255) & ~(size_t)255;
        return r;
    };
    float* A = (float*)alloc((size_t)NN * HID * 4);
    float* B = (float*)alloc((size_t)NN * HID * 4);
    float* C = (float*)alloc((size_t)NN * HID * 4);
    float* gsum = (float*)alloc((size_t)NG * HID * 4);
    int* gcnt = (int*)alloc((size_t)NG * 4);
    int* cnt = (int*)alloc((size_t)NN * 4);
    int* row_ptr = (int*)alloc((size_t)(NN + 1) * 4);
    int* cursor = (int*)alloc((size_t)NN * 4);
    int* esrc = (int*)alloc((size_t)NE * 4);
    int* bsums = (int*)alloc(256 * 4);

    hipMemsetAsync(cnt, 0, (size_t)NN * 4, stream);
    hipMemsetAsync(gsum, 0, (size_t)NG * HID * 4, stream);
    hipMemsetAsync(gcnt, 0, (size_t)NG * 4, stream);

    const int NB_E = (NE + 255) / 256;     // 3125
    const int NB_SCAN = (NN + 255) / 256;  // 196
    const int GB = (NN + 31) / 32;         // 1563

    // CSR by destination node
    hist_kernel<<<NB_E, 256, 0, stream>>>(dst, cnt);
    scan_block_kernel<<<NB_SCAN, 256, 0, stream>>>(cnt, row_ptr, bsums, NN);
    scan_sums_kernel<<<1, 256, 0, stream>>>(bsums, NB_SCAN);
    scan_add_kernel<<<NB_SCAN, 256, 0, stream>>>(row_ptr, cursor, bsums, NN);
    fill_csr_kernel<<<NB_E, 256, 0, stream>>>(src, dst, cursor, esrc);

    // layer 0: res0 = x @ Wres -> C; t = x + agg(x) -> A; u = relu(t@W1+b1) -> B;
    //          h0 = relu(u@W2+b2 + res0) -> A
    gemm_kernel<64, 0><<<GB, 256, 0, stream>>>(x, l0_Wres, nullptr, nullptr, C, NN);
    agg_kernel<64><<<(NN + 3) / 4, 256, 0, stream>>>(x, row_ptr, esrc, A);
    gemm_kernel<64, 1><<<GB, 256, 0, stream>>>(A, l0_W1, l0_b1, nullptr, B, NN);
    gemm_kernel<128, 2><<<GB, 256, 0, stream>>>(B, l0_W2, l0_b2, C, A, NN);

    // layers 1..3 (identity residual), rotating buffers
    float* hcur = A;
    float* tb = C;
    float* ub = B;
    for (int l = 0; l < 3; ++l) {
        agg_kernel<128><<<(NN + 3) / 4, 256, 0, stream>>>(hcur, row_ptr, esrc, tb);
        gemm_kernel<128, 1><<<GB, 256, 0, stream>>>(tb, Ws1 + (size_t)l * HID * HID,
                                                    bs1 + (size_t)l * HID, nullptr, ub, NN);
        gemm_kernel<128, 2><<<GB, 256, 0, stream>>>(ub, Ws2 + (size_t)l * HID * HID,
                                                    bs2 + (size_t)l * HID, hcur, tb, NN);
        float* t2 = hcur;
        hcur = tb;
        tb = t2;
    }

    // global mean pool + FC head
    pool_sum_kernel<<<(NN * 64 + 255) / 256, 256, 0, stream>>>(hcur, batch, gsum);
    pool_cnt_kernel<<<NB_SCAN, 256, 0, stream>>>(batch, gcnt);
    head_kernel<<<NG, 128, 0, stream>>>(gsum, gcnt, fW1, fb1, fW2, fb2, out);
}

// Round 2
// 679.175 us; speedup vs baseline: 1.2219x; 1.2219x over previous
//
#include <hip/hip_runtime.h>

#define NN 50000
#define NE 800000
#define IND 64
#define HID 128
#define NG 1024

typedef short bf16x8 __attribute__((ext_vector_type(8)));
typedef float f32x4 __attribute__((ext_vector_type(4)));

static __device__ __forceinline__ unsigned short f2bf(float f) {
    unsigned int u = __float_as_uint(f);
    return (unsigned short)((u + 0x7FFFu + ((u >> 16) & 1u)) >> 16);
}
static __device__ __forceinline__ float bf2f(unsigned short h) {
    return __uint_as_float(((unsigned int)h) << 16);
}
static __device__ __forceinline__ float4 f4zero() { return make_float4(0.f, 0.f, 0.f, 0.f); }

// ---------------- CSR build ----------------
__global__ void hist_kernel(const int* __restrict__ dst, int* __restrict__ cnt) {
    int i = blockIdx.x * 256 + threadIdx.x;
    if (i < NE) atomicAdd(&cnt[dst[i]], 1);
}

__global__ void scan_block_kernel(const int* __restrict__ in, int* __restrict__ out,
                                  int* __restrict__ bsums, int n) {
    __shared__ int s[256];
    int tid = threadIdx.x;
    int i = blockIdx.x * 256 + tid;
    int v = (i < n) ? in[i] : 0;
    s[tid] = v;
    __syncthreads();
    for (int off = 1; off < 256; off <<= 1) {
        int add = (tid >= off) ? s[tid - off] : 0;
        __syncthreads();
        s[tid] += add;
        __syncthreads();
    }
    if (i < n) out[i] = s[tid] - v;
    if (tid == 255) bsums[blockIdx.x] = s[255];
}

__global__ void scan_sums_kernel(int* __restrict__ bsums, int nb) {
    __shared__ int s[256];
    int tid = threadIdx.x;
    int v = (tid < nb) ? bsums[tid] : 0;
    s[tid] = v;
    __syncthreads();
    for (int off = 1; off < 256; off <<= 1) {
        int add = (tid >= off) ? s[tid - off] : 0;
        __syncthreads();
        s[tid] += add;
        __syncthreads();
    }
    if (tid < nb) bsums[tid] = s[tid] - v;
}

__global__ void scan_add_kernel(int* __restrict__ row_ptr, int* __restrict__ cursor,
                                const int* __restrict__ bsums, int n) {
    int i = blockIdx.x * 256 + threadIdx.x;
    if (i < n) {
        int v = row_ptr[i] + bsums[blockIdx.x];
        row_ptr[i] = v;
        cursor[i] = v;
    }
    if (blockIdx.x == 0 && threadIdx.x == 0) row_ptr[n] = NE;
}

__global__ void fill_csr_kernel(const int* __restrict__ src, const int* __restrict__ dst,
                                int* __restrict__ cursor, int* __restrict__ esrc) {
    int i = blockIdx.x * 256 + threadIdx.x;
    if (i < NE) {
        int p = atomicAdd(&cursor[dst[i]], 1);
        esrc[p] = src[i];
    }
}

// ---------------- weight convert: W[K][128] fp32 -> Wt hi/lo [128][K] bf16 ----------------
__global__ void convert_w(const float* __restrict__ W, short* __restrict__ hi,
                          short* __restrict__ lo, int K, int total) {
    int t = blockIdx.x * 256 + threadIdx.x;
    if (t >= total) return;
    int m = t / (K * 128);
    int r = t - m * K * 128;
    int n = r / K, k = r - n * K;
    float w = W[(size_t)m * K * 128 + k * 128 + n];
    unsigned short h = f2bf(w);
    float rem = w - bf2f(h);
    hi[t] = (short)h;
    lo[t] = (short)f2bf(rem);
}

__global__ void to_bf16_kernel(const float* __restrict__ s, short* __restrict__ d, int total) {
    int i = blockIdx.x * 256 + threadIdx.x;
    if (i < total) d[i] = (short)f2bf(s[i]);
}

// ---------------- fp32 aggregation (fallback) ----------------
template <int D>
__global__ void agg_kernel(const float* __restrict__ x, const int* __restrict__ row_ptr,
                           const int* __restrict__ esrc, float* __restrict__ out) {
    int wv = threadIdx.x >> 6, lane = threadIdx.x & 63;
    int n = blockIdx.x * 4 + wv;
    if (n >= NN) return;
    int beg = row_ptr[n], end = row_ptr[n + 1];
    if (D == 128) {
        const float2* xp = (const float2*)x;
        float2 acc = xp[(size_t)n * 64 + lane];
        for (int e = beg; e < end; ++e) {
            int s = esrc[e];
            float2 v = xp[(size_t)s * 64 + lane];
            acc.x += v.x;
            acc.y += v.y;
        }
        ((float2*)out)[(size_t)n * 64 + lane] = acc;
    } else {
        float acc = x[(size_t)n * 64 + lane];
        for (int e = beg; e < end; ++e) acc += x[(size_t)esrc[e] * 64 + lane];
        out[(size_t)n * 64 + lane] = acc;
    }
}

// ---------------- bf16 gather aggregation, exact fp32 self term ----------------
__global__ void agg128b_kernel(const unsigned int* __restrict__ hb, const float* __restrict__ hf,
                               const int* __restrict__ rp, const int* __restrict__ es,
                               float* __restrict__ t) {
    int wv = threadIdx.x >> 6, lane = threadIdx.x & 63;
    int n = blockIdx.x * 4 + wv;
    if (n >= NN) return;
    int beg = rp[n], end = rp[n + 1];
    float2 acc = ((const float2*)hf)[(size_t)n * 64 + lane];
    int e = beg;
    for (; e + 4 <= end; e += 4) {
        int s0 = es[e], s1 = es[e + 1], s2 = es[e + 2], s3 = es[e + 3];
        unsigned int v0 = hb[(size_t)s0 * 64 + lane];
        unsigned int v1 = hb[(size_t)s1 * 64 + lane];
        unsigned int v2 = hb[(size_t)s2 * 64 + lane];
        unsigned int v3 = hb[(size_t)s3 * 64 + lane];
        acc.x += __uint_as_float(v0 << 16) + __uint_as_float(v1 << 16) +
                 __uint_as_float(v2 << 16) + __uint_as_float(v3 << 16);
        acc.y += __uint_as_float(v0 & 0xffff0000u) + __uint_as_float(v1 & 0xffff0000u) +
                 __uint_as_float(v2 & 0xffff0000u) + __uint_as_float(v3 & 0xffff0000u);
    }
    for (; e < end; ++e) {
        unsigned int v = hb[(size_t)es[e] * 64 + lane];
        acc.x += __uint_as_float(v << 16);
        acc.y += __uint_as_float(v & 0xffff0000u);
    }
    ((float2*)t)[(size_t)n * 64 + lane] = acc;
}

__global__ void agg64b_kernel(const unsigned short* __restrict__ xb, const float* __restrict__ xf,
                              const int* __restrict__ rp, const int* __restrict__ es,
                              float* __restrict__ t) {
    int wv = threadIdx.x >> 6, lane = threadIdx.x & 63;
    int n = blockIdx.x * 4 + wv;
    if (n >= NN) return;
    int beg = rp[n], end = rp[n + 1];
    float acc = xf[(size_t)n * 64 + lane];
    int e = beg;
    for (; e + 4 <= end; e += 4) {
        int s0 = es[e], s1 = es[e + 1], s2 = es[e + 2], s3 = es[e + 3];
        float a0 = bf2f(xb[(size_t)s0 * 64 + lane]);
        float a1 = bf2f(xb[(size_t)s1 * 64 + lane]);
        float a2 = bf2f(xb[(size_t)s2 * 64 + lane]);
        float a3 = bf2f(xb[(size_t)s3 * 64 + lane]);
        acc += a0 + a1 + a2 + a3;
    }
    for (; e < end; ++e) acc += bf2f(xb[(size_t)es[e] * 64 + lane]);
    t[(size_t)n * 64 + lane] = acc;
}

// ---------------- MFMA GEMM, split-bf16 (3-term): out = act(in[N,K] @ W[K,128] + b [+res]) ----
// MODE 0: plain; MODE 1: relu; MODE 2: relu(+res). outB: optional bf16 copy of output.
// Block: 256 thr (4 waves), 64 rows/block; wave w owns rows w*16..w*16+15, all 128 cols.
template <int K, int MODE>
__global__ __launch_bounds__(256, 4) void gemm_mfma(
    const float* __restrict__ in, const short* __restrict__ WtHi, const short* __restrict__ WtLo,
    const float* __restrict__ bias, const float* __restrict__ res, float* __restrict__ out,
    short* __restrict__ outB, int nRows) {
    constexpr int NKC = K / 32;
    __shared__ short sHi[64 * K];
    __shared__ short sLo[64 * K];
    int tid = threadIdx.x;
    int rowBase = blockIdx.x * 64;

    // stage + split input tile [64][K], XOR-swizzled (idx ^ ((row&7)<<3))
    for (int i = tid; i < 64 * K / 4; i += 256) {
        int r = i / (K / 4), c4 = i - r * (K / 4);
        int row = rowBase + r;
        float4 v = f4zero();
        if (row < nRows) v = ((const float4*)(in + (size_t)row * K))[c4];
        unsigned short hx = f2bf(v.x), hy = f2bf(v.y), hz = f2bf(v.z), hw = f2bf(v.w);
        unsigned short lx = f2bf(v.x - bf2f(hx)), ly = f2bf(v.y - bf2f(hy));
        unsigned short lz = f2bf(v.z - bf2f(hz)), lw = f2bf(v.w - bf2f(hw));
        int sidx = (r * K + c4 * 4) ^ ((r & 7) << 3);
        short4 hv = {(short)hx, (short)hy, (short)hz, (short)hw};
        short4 lv = {(short)lx, (short)ly, (short)lz, (short)lw};
        *(short4*)(sHi + sidx) = hv;
        *(short4*)(sLo + sidx) = lv;
    }
    __syncthreads();

    int lane = tid & 63, wv = tid >> 6;
    int m = lane & 15, g = lane >> 4;
    int rloc = wv * 16 + m;

    bf16x8 ahi[NKC], alo[NKC];
#pragma unroll
    for (int kc = 0; kc < NKC; ++kc) {
        int idx = (rloc * K + kc * 32 + g * 8) ^ ((rloc & 7) << 3);
        ahi[kc] = *(const bf16x8*)(sHi + idx);
        alo[kc] = *(const bf16x8*)(sLo + idx);
    }

#pragma unroll
    for (int ct = 0; ct < 8; ++ct) {
        int col = ct * 16 + m;
        float bv = bias ? bias[col] : 0.f;
        f32x4 acc = {bv, bv, bv, bv};
#pragma unroll
        for (int kc = 0; kc < NKC; ++kc) {
            bf16x8 bhi = *(const bf16x8*)(WtHi + col * K + kc * 32 + g * 8);
            bf16x8 blo = *(const bf16x8*)(WtLo + col * K + kc * 32 + g * 8);
            acc = __builtin_amdgcn_mfma_f32_16x16x32_bf16(ahi[kc], bhi, acc, 0, 0, 0);
            acc = __builtin_amdgcn_mfma_f32_16x16x32_bf16(alo[kc], bhi, acc, 0, 0, 0);
            acc = __builtin_amdgcn_mfma_f32_16x16x32_bf16(ahi[kc], blo, acc, 0, 0, 0);
        }
#pragma unroll
        for (int i = 0; i < 4; ++i) {
            int row = rowBase + wv * 16 + g * 4 + i;  // C/D: col=lane&15, row=(lane>>4)*4+reg
            if (row >= nRows) continue;
            float v = acc[i];
            if (MODE == 2) v = fmaxf(v + res[(size_t)row * 128 + col], 0.f);
            else if (MODE == 1) v = fmaxf(v, 0.f);
            out[(size_t)row * 128 + col] = v;
            if (outB) outB[(size_t)row * 128 + col] = (short)f2bf(v);
        }
    }
}

// ---------------- fused mean-pool + FC head (batch is sorted -> binary search ranges) --------
static __device__ __forceinline__ int lbound(const int* __restrict__ a, int n, int v) {
    int lo = 0, hi = n;
    while (lo < hi) {
        int mid = (lo + hi) >> 1;
        if (a[mid] < v) lo = mid + 1;
        else hi = mid;
    }
    return lo;
}

__global__ void head_kernel(const float* __restrict__ h, const int* __restrict__ batch,
                            const float* __restrict__ fW1, const float* __restrict__ fb1,
                            const float* __restrict__ fW2, const float* __restrict__ fb2,
                            float* __restrict__ out) {
    __shared__ float sp[128];
    __shared__ float su[128];
    __shared__ int sr[2];
    int g = blockIdx.x, t = threadIdx.x;
    if (t == 0) sr[0] = lbound(batch, NN, g);
    if (t == 1) sr[1] = lbound(batch, NN, g + 1);
    __syncthreads();
    int beg = sr[0], end = sr[1];
    float acc = 0.f;
    for (int i = beg; i < end; ++i) acc += h[(size_t)i * 128 + t];
    sp[t] = acc / (float)max(end - beg, 1);
    __syncthreads();
    float a = fb1[t];
#pragma unroll 4
    for (int k = 0; k < 128; ++k) a = fmaf(sp[k], fW1[k * 128 + t], a);
    a = a > 0.f ? a : 0.01f * a;
    su[t] = a * fW2[t];
    __syncthreads();
    for (int s2 = 64; s2 > 0; s2 >>= 1) {
        if (t < s2) su[t] += su[t + s2];
        __syncthreads();
    }
    if (t == 0) out[g] = su[0] + fb2[0];
}

extern "C" void kernel_launch(void* const* d_in, const int* in_sizes, int n_in,
                              void* d_out, int out_size, void* d_ws, size_t ws_size,
                              hipStream_t stream) {
    const float* x = (const float*)d_in[0];
    const int* eidx = (const int*)d_in[1];
    const int* src = eidx;
    const int* dst = eidx + NE;
    const int* batch = (const int*)d_in[2];
    const float* l0_W1 = (const float*)d_in[3];
    const float* l0_b1 = (const float*)d_in[4];
    const float* l0_W2 = (const float*)d_in[5];
    const float* l0_b2 = (const float*)d_in[6];
    const float* l0_Wres = (const float*)d_in[7];
    const float* Ws1 = (const float*)d_in[8];
    const float* bs1 = (const float*)d_in[9];
    const float* Ws2 = (const float*)d_in[10];
    const float* bs2 = (const float*)d_in[11];
    const float* fW1 = (const float*)d_in[12];
    const float* fb1 = (const float*)d_in[13];
    const float* fW2 = (const float*)d_in[14];
    const float* fb2 = (const float*)d_in[15];
    float* out = (float*)d_out;

    size_t used = 0;
    auto alloc = [&](size_t bytes) -> char* {
        char* r = (char*)d_ws + used;
        used = (used + bytes + 255) & ~(size_t)255;
        return r;
    };
    float* A = (float*)alloc((size_t)NN * HID * 4);
    float* B = (float*)alloc((size_t)NN * HID * 4);
    float* C = (float*)alloc((size_t)NN * HID * 4);
    int* cnt = (int*)alloc((size_t)NN * 4);
    int* row_ptr = (int*)alloc((size_t)(NN + 1) * 4);
    int* cursor = (int*)alloc((size_t)NN * 4);
    int* esrc = (int*)alloc((size_t)NE * 4);
    int* bsums = (int*)alloc(256 * 4);
    short* wresHi = (short*)alloc(128 * 64 * 2);
    short* wresLo = (short*)alloc(128 * 64 * 2);
    short* w1Hi = (short*)alloc(128 * 64 * 2);
    short* w1Lo = (short*)alloc(128 * 64 * 2);
    short* w2Hi = (short*)alloc(128 * 128 * 2);
    short* w2Lo = (short*)alloc(128 * 128 * 2);
    short* ws1Hi = (short*)alloc(3 * 128 * 128 * 2);
    short* ws1Lo = (short*)alloc(3 * 128 * 128 * 2);
    short* ws2Hi = (short*)alloc(3 * 128 * 128 * 2);
    short* ws2Lo = (short*)alloc(3 * 128 * 128 * 2);
    // optional bf16 buffers for half-traffic aggregation
    size_t needB = ((size_t)NN * HID * 2 + 255 + (size_t)NN * IND * 2 + 255);
    bool useB = (used + needB) <= ws_size;
    short* hb = nullptr;
    short* xb = nullptr;
    if (useB) {
        hb = (short*)alloc((size_t)NN * HID * 2);
        xb = (short*)alloc((size_t)NN * IND * 2);
    }

    hipMemsetAsync(cnt, 0, (size_t)NN * 4, stream);

    const int NB_E = (NE + 255) / 256;
    const int NB_SCAN = (NN + 255) / 256;
    const int GB = (NN + 63) / 64;
    const int AGGB = (NN + 3) / 4;

    // weight splits (tiny)
    convert_w<<<(8192 + 255) / 256, 256, 0, stream>>>(l0_Wres, wresHi, wresLo, 64, 8192);
    convert_w<<<(8192 + 255) / 256, 256, 0, stream>>>(l0_W1, w1Hi, w1Lo, 64, 8192);
    convert_w<<<(16384 + 255) / 256, 256, 0, stream>>>(l0_W2, w2Hi, w2Lo, 128, 16384);
    convert_w<<<(49152 + 255) / 256, 256, 0, stream>>>(Ws1, ws1Hi, ws1Lo, 128, 49152);
    convert_w<<<(49152 + 255) / 256, 256, 0, stream>>>(Ws2, ws2Hi, ws2Lo, 128, 49152);
    if (useB)
        to_bf16_kernel<<<(NN * IND + 255) / 256, 256, 0, stream>>>(x, xb, NN * IND);

    // CSR by destination
    hist_kernel<<<NB_E, 256, 0, stream>>>(dst, cnt);
    scan_block_kernel<<<NB_SCAN, 256, 0, stream>>>(cnt, row_ptr, bsums, NN);
    scan_sums_kernel<<<1, 256, 0, stream>>>(bsums, NB_SCAN);
    scan_add_kernel<<<NB_SCAN, 256, 0, stream>>>(row_ptr, cursor, bsums, NN);
    fill_csr_kernel<<<NB_E, 256, 0, stream>>>(src, dst, cursor, esrc);

    // layer 0
    gemm_mfma<64, 0><<<GB, 256, 0, stream>>>(x, wresHi, wresLo, nullptr, nullptr, C, nullptr, NN);
    if (useB)
        agg64b_kernel<<<AGGB, 256, 0, stream>>>((const unsigned short*)xb, x, row_ptr, esrc, A);
    else
        agg_kernel<64><<<AGGB, 256, 0, stream>>>(x, row_ptr, esrc, A);
    gemm_mfma<64, 1><<<GB, 256, 0, stream>>>(A, w1Hi, w1Lo, l0_b1, nullptr, B, nullptr, NN);
    gemm_mfma<128, 2><<<GB, 256, 0, stream>>>(B, w2Hi, w2Lo, l0_b2, C, A, hb, NN);

    // layers 1..3
    float* hcur = A;
    float* tb = C;
    float* ub = B;
    for (int l = 0; l < 3; ++l) {
        if (useB)
            agg128b_kernel<<<AGGB, 256, 0, stream>>>((const unsigned int*)hb, hcur, row_ptr, esrc, tb);
        else
            agg_kernel<128><<<AGGB, 256, 0, stream>>>(hcur, row_ptr, esrc, tb);
        gemm_mfma<128, 1><<<GB, 256, 0, stream>>>(tb, ws1Hi + (size_t)l * 16384,
                                                  ws1Lo + (size_t)l * 16384, bs1 + (size_t)l * HID,
                                                  nullptr, ub, nullptr, NN);
        gemm_mfma<128, 2><<<GB, 256, 0, stream>>>(ub, ws2Hi + (size_t)l * 16384,
                                                  ws2Lo + (size_t)l * 16384, bs2 + (size_t)l * HID,
                                                  hcur, tb, hb, NN);
        float* t2 = hcur;
        hcur = tb;
        tb = t2;
    }

    // fused mean-pool + head
    head_kernel<<<NG, 128, 0, stream>>>(hcur, batch, fW1, fb1, fW2, fb2, out);
}

// Round 5
// 611.441 us; speedup vs baseline: 1.3573x; 1.1108x over previous
//
#include <hip/hip_runtime.h>

#define NN 50000
#define NE 800000
#define IND 64
#define HID 128
#define NG 1024

#define NBK 391   // buckets of 128 dst nodes
#define BCAP 2560 // padded capacity per bucket (avg 2046, +11 sigma)

typedef short bf16x8 __attribute__((ext_vector_type(8)));
typedef float f32x4 __attribute__((ext_vector_type(4)));

static __device__ __forceinline__ unsigned short f2bf(float f) {
    unsigned int u = __float_as_uint(f);
    return (unsigned short)((u + 0x7FFFu + ((u >> 16) & 1u)) >> 16);
}
static __device__ __forceinline__ float bf2f(unsigned short h) {
    return __uint_as_float(((unsigned int)h) << 16);
}
static __device__ __forceinline__ float4 f4zero() { return make_float4(0.f, 0.f, 0.f, 0.f); }

// ---------------- bucketed CSR build ----------------
// pass 1: bin edges (packed src|dst<<16) into 391 fixed-capacity buckets by dst>>7
__global__ void bin_kernel(const int* __restrict__ src, const int* __restrict__ dst,
                           int* __restrict__ bcur, unsigned int* __restrict__ bedge) {
    __shared__ int hist[NBK];
    __shared__ int base[NBK];
    int tid = threadIdx.x;
    for (int i = tid; i < NBK; i += 256) hist[i] = 0;
    __syncthreads();
    int e0 = blockIdx.x * 4096;
    unsigned int pk[16];
    int bk[16], lo[16];
#pragma unroll
    for (int j = 0; j < 16; ++j) {
        int e = e0 + j * 256 + tid;
        bk[j] = -1;
        if (e < NE) {
            int s = src[e], d = dst[e];
            pk[j] = (unsigned int)s | ((unsigned int)d << 16);
            bk[j] = d >> 7;
            lo[j] = atomicAdd(&hist[bk[j]], 1);
        }
    }
    __syncthreads();
    for (int i = tid; i < NBK; i += 256)
        base[i] = hist[i] ? atomicAdd(&bcur[i], hist[i]) : 0;
    __syncthreads();
#pragma unroll
    for (int j = 0; j < 16; ++j) {
        if (bk[j] >= 0) {
            int idx = base[bk[j]] + lo[j];
            if (idx < BCAP) bedge[(size_t)bk[j] * BCAP + idx] = pk[j];
        }
    }
}

// pass 2: per-bucket local CSR (row_beg/row_end point into padded esrc layout)
__global__ void build_csr_kernel(const unsigned int* __restrict__ bedge,
                                 const int* __restrict__ bcur, int* __restrict__ row_beg,
                                 int* __restrict__ row_end, int* __restrict__ esrc) {
    __shared__ unsigned int se[BCAP];
    __shared__ int h[128], sc[128], cur[128];
    int b = blockIdx.x, tid = threadIdx.x;
    int cnt = min(bcur[b], BCAP);
    for (int i = tid; i < cnt; i += 256) se[i] = bedge[(size_t)b * BCAP + i];
    if (tid < 128) h[tid] = 0;
    __syncthreads();
    for (int i = tid; i < cnt; i += 256) atomicAdd(&h[(se[i] >> 16) & 127], 1);
    __syncthreads();
    if (tid < 128) sc[tid] = h[tid];
    __syncthreads();
    for (int off = 1; off < 128; off <<= 1) {
        int add = 0;
        if (tid < 128 && tid >= off) add = sc[tid - off];
        __syncthreads();
        if (tid < 128) sc[tid] += add;
        __syncthreads();
    }
    if (tid < 128) {
        int ex = sc[tid] - h[tid];
        int n = (b << 7) + tid;
        if (n < NN) {
            row_beg[n] = b * BCAP + ex;
            row_end[n] = b * BCAP + sc[tid];
        }
        cur[tid] = ex;
    }
    __syncthreads();
    for (int i = tid; i < cnt; i += 256) {
        unsigned int v = se[i];
        int dl = (v >> 16) & 127;
        int pos = atomicAdd(&cur[dl], 1);
        esrc[(size_t)b * BCAP + pos] = (int)(v & 0xffffu);
    }
}

// ---------------- weight convert (all weights, one launch) ----------------
// W[K][128] fp32 -> Wt hi/lo [128][K] bf16; 131072 total elements
__global__ void convert_all(const float* __restrict__ Wres, const float* __restrict__ W1,
                            const float* __restrict__ W2, const float* __restrict__ Ws1,
                            const float* __restrict__ Ws2, short* __restrict__ wresHi,
                            short* __restrict__ wresLo, short* __restrict__ w1Hi,
                            short* __restrict__ w1Lo, short* __restrict__ w2Hi,
                            short* __restrict__ w2Lo, short* __restrict__ ws1Hi,
                            short* __restrict__ ws1Lo, short* __restrict__ ws2Hi,
                            short* __restrict__ ws2Lo) {
    int t = blockIdx.x * 256 + threadIdx.x;
    const float* W;
    short *hi, *lo;
    int K, idx;
    if (t < 8192) { W = Wres; hi = wresHi; lo = wresLo; K = 64; idx = t; }
    else if (t < 16384) { W = W1; hi = w1Hi; lo = w1Lo; K = 64; idx = t - 8192; }
    else if (t < 32768) { W = W2; hi = w2Hi; lo = w2Lo; K = 128; idx = t - 16384; }
    else if (t < 81920) { W = Ws1; hi = ws1Hi; lo = ws1Lo; K = 128; idx = t - 32768; }
    else { W = Ws2; hi = ws2Hi; lo = ws2Lo; K = 128; idx = t - 81920; }
    int m = idx / (K * 128);
    int r = idx - m * K * 128;
    int n = r / K, k = r - n * K;
    float w = W[(size_t)m * K * 128 + k * 128 + n];
    unsigned short hh = f2bf(w);
    hi[idx] = (short)hh;
    lo[idx] = (short)f2bf(w - bf2f(hh));
}

__global__ void to_bf16_kernel(const float* __restrict__ s, short* __restrict__ d, int total) {
    int i = blockIdx.x * 256 + threadIdx.x;
    if (i < total) d[i] = (short)f2bf(s[i]);
}

// ---------------- fp32 aggregation (fallback) ----------------
template <int D>
__global__ void agg_kernel(const float* __restrict__ x, const int* __restrict__ row_beg,
                           const int* __restrict__ row_end, const int* __restrict__ esrc,
                           float* __restrict__ out) {
    int wv = threadIdx.x >> 6, lane = threadIdx.x & 63;
    int n = blockIdx.x * 4 + wv;
    if (n >= NN) return;
    int beg = row_beg[n], end = row_end[n];
    if (D == 128) {
        const float2* xp = (const float2*)x;
        float2 acc = xp[(size_t)n * 64 + lane];
        for (int e = beg; e < end; ++e) {
            int s = esrc[e];
            float2 v = xp[(size_t)s * 64 + lane];
            acc.x += v.x;
            acc.y += v.y;
        }
        ((float2*)out)[(size_t)n * 64 + lane] = acc;
    } else {
        float acc = x[(size_t)n * 64 + lane];
        for (int e = beg; e < end; ++e) acc += x[(size_t)esrc[e] * 64 + lane];
        out[(size_t)n * 64 + lane] = acc;
    }
}

// ---------------- bf16 gather aggregation, exact fp32 self term ----------------
__global__ void agg128b_kernel(const unsigned int* __restrict__ hb, const float* __restrict__ hf,
                               const int* __restrict__ row_beg, const int* __restrict__ row_end,
                               const int* __restrict__ es, float* __restrict__ t) {
    int wv = threadIdx.x >> 6, lane = threadIdx.x & 63;
    int n = blockIdx.x * 4 + wv;
    if (n >= NN) return;
    int beg = row_beg[n], end = row_end[n];
    float2 acc = ((const float2*)hf)[(size_t)n * 64 + lane];
    int e = beg;
    for (; e + 4 <= end; e += 4) {
        int s0 = es[e], s1 = es[e + 1], s2 = es[e + 2], s3 = es[e + 3];
        unsigned int v0 = hb[(size_t)s0 * 64 + lane];
        unsigned int v1 = hb[(size_t)s1 * 64 + lane];
        unsigned int v2 = hb[(size_t)s2 * 64 + lane];
        unsigned int v3 = hb[(size_t)s3 * 64 + lane];
        acc.x += __uint_as_float(v0 << 16) + __uint_as_float(v1 << 16) +
                 __uint_as_float(v2 << 16) + __uint_as_float(v3 << 16);
        acc.y += __uint_as_float(v0 & 0xffff0000u) + __uint_as_float(v1 & 0xffff0000u) +
                 __uint_as_float(v2 & 0xffff0000u) + __uint_as_float(v3 & 0xffff0000u);
    }
    for (; e < end; ++e) {
        unsigned int v = hb[(size_t)es[e] * 64 + lane];
        acc.x += __uint_as_float(v << 16);
        acc.y += __uint_as_float(v & 0xffff0000u);
    }
    ((float2*)t)[(size_t)n * 64 + lane] = acc;
}

__global__ void agg64b_kernel(const unsigned short* __restrict__ xb, const float* __restrict__ xf,
                              const int* __restrict__ row_beg, const int* __restrict__ row_end,
                              const int* __restrict__ es, float* __restrict__ t) {
    int wv = threadIdx.x >> 6, lane = threadIdx.x & 63;
    int n = blockIdx.x * 4 + wv;
    if (n >= NN) return;
    int beg = row_beg[n], end = row_end[n];
    float acc = xf[(size_t)n * 64 + lane];
    int e = beg;
    for (; e + 4 <= end; e += 4) {
        int s0 = es[e], s1 = es[e + 1], s2 = es[e + 2], s3 = es[e + 3];
        float a0 = bf2f(xb[(size_t)s0 * 64 + lane]);
        float a1 = bf2f(xb[(size_t)s1 * 64 + lane]);
        float a2 = bf2f(xb[(size_t)s2 * 64 + lane]);
        float a3 = bf2f(xb[(size_t)s3 * 64 + lane]);
        acc += a0 + a1 + a2 + a3;
    }
    for (; e < end; ++e) acc += bf2f(xb[(size_t)es[e] * 64 + lane]);
    t[(size_t)n * 64 + lane] = acc;
}

// ---------------- MFMA GEMM, split-bf16 (3-term) ----------------
template <int K, int MODE>
__global__ __launch_bounds__(256, 4) void gemm_mfma(
    const float* __restrict__ in, const short* __restrict__ WtHi, const short* __restrict__ WtLo,
    const float* __restrict__ bias, const float* __restrict__ res, float* __restrict__ out,
    short* __restrict__ outB, int nRows) {
    constexpr int NKC = K / 32;
    __shared__ short sHi[64 * K];
    __shared__ short sLo[64 * K];
    int tid = threadIdx.x;
    int rowBase = blockIdx.x * 64;

    for (int i = tid; i < 64 * K / 4; i += 256) {
        int r = i / (K / 4), c4 = i - r * (K / 4);
        int row = rowBase + r;
        float4 v = f4zero();
        if (row < nRows) v = ((const float4*)(in + (size_t)row * K))[c4];
        unsigned short hx = f2bf(v.x), hy = f2bf(v.y), hz = f2bf(v.z), hw = f2bf(v.w);
        unsigned short lx = f2bf(v.x - bf2f(hx)), ly = f2bf(v.y - bf2f(hy));
        unsigned short lz = f2bf(v.z - bf2f(hz)), lw = f2bf(v.w - bf2f(hw));
        int sidx = (r * K + c4 * 4) ^ ((r & 7) << 3);
        short4 hv = {(short)hx, (short)hy, (short)hz, (short)hw};
        short4 lv = {(short)lx, (short)ly, (short)lz, (short)lw};
        *(short4*)(sHi + sidx) = hv;
        *(short4*)(sLo + sidx) = lv;
    }
    __syncthreads();

    int lane = tid & 63, wv = tid >> 6;
    int m = lane & 15, g = lane >> 4;
    int rloc = wv * 16 + m;

    bf16x8 ahi[NKC], alo[NKC];
#pragma unroll
    for (int kc = 0; kc < NKC; ++kc) {
        int idx = (rloc * K + kc * 32 + g * 8) ^ ((rloc & 7) << 3);
        ahi[kc] = *(const bf16x8*)(sHi + idx);
        alo[kc] = *(const bf16x8*)(sLo + idx);
    }

#pragma unroll
    for (int ct = 0; ct < 8; ++ct) {
        int col = ct * 16 + m;
        float bv = bias ? bias[col] : 0.f;
        f32x4 acc = {bv, bv, bv, bv};
#pragma unroll
        for (int kc = 0; kc < NKC; ++kc) {
            bf16x8 bhi = *(const bf16x8*)(WtHi + col * K + kc * 32 + g * 8);
            bf16x8 blo = *(const bf16x8*)(WtLo + col * K + kc * 32 + g * 8);
            acc = __builtin_amdgcn_mfma_f32_16x16x32_bf16(ahi[kc], bhi, acc, 0, 0, 0);
            acc = __builtin_amdgcn_mfma_f32_16x16x32_bf16(alo[kc], bhi, acc, 0, 0, 0);
            acc = __builtin_amdgcn_mfma_f32_16x16x32_bf16(ahi[kc], blo, acc, 0, 0, 0);
        }
#pragma unroll
        for (int i = 0; i < 4; ++i) {
            int row = rowBase + wv * 16 + g * 4 + i;
            if (row >= nRows) continue;
            float v = acc[i];
            if (MODE == 2) v = fmaxf(v + res[(size_t)row * 128 + col], 0.f);
            else if (MODE == 1) v = fmaxf(v, 0.f);
            out[(size_t)row * 128 + col] = v;
            if (outB) outB[(size_t)row * 128 + col] = (short)f2bf(v);
        }
    }
}

// ---------------- fused mean-pool + FC head ----------------
static __device__ __forceinline__ int lbound(const int* __restrict__ a, int n, int v) {
    int lo = 0, hi = n;
    while (lo < hi) {
        int mid = (lo + hi) >> 1;
        if (a[mid] < v) lo = mid + 1;
        else hi = mid;
    }
    return lo;
}

__global__ void head_kernel(const float* __restrict__ h, const int* __restrict__ batch,
                            const float* __restrict__ fW1, const float* __restrict__ fb1,
                            const float* __restrict__ fW2, const float* __restrict__ fb2,
                            float* __restrict__ out) {
    __shared__ float sp[128];
    __shared__ float su[128];
    __shared__ int sr[2];
    int g = blockIdx.x, t = threadIdx.x;
    if (t == 0) sr[0] = lbound(batch, NN, g);
    if (t == 1) sr[1] = lbound(batch, NN, g + 1);
    __syncthreads();
    int beg = sr[0], end = sr[1];
    float acc = 0.f;
    for (int i = beg; i < end; ++i) acc += h[(size_t)i * 128 + t];
    sp[t] = acc / (float)max(end - beg, 1);
    __syncthreads();
    float a = fb1[t];
#pragma unroll 4
    for (int k = 0; k < 128; ++k) a = fmaf(sp[k], fW1[k * 128 + t], a);
    a = a > 0.f ? a : 0.01f * a;
    su[t] = a * fW2[t];
    __syncthreads();
    for (int s2 = 64; s2 > 0; s2 >>= 1) {
        if (t < s2) su[t] += su[t + s2];
        __syncthreads();
    }
    if (t == 0) out[g] = su[0] + fb2[0];
}

extern "C" void kernel_launch(void* const* d_in, const int* in_sizes, int n_in,
                              void* d_out, int out_size, void* d_ws, size_t ws_size,
                              hipStream_t stream) {
    const float* x = (const float*)d_in[0];
    const int* eidx = (const int*)d_in[1];
    const int* src = eidx;
    const int* dst = eidx + NE;
    const int* batch = (const int*)d_in[2];
    const float* l0_W1 = (const float*)d_in[3];
    const float* l0_b1 = (const float*)d_in[4];
    const float* l0_W2 = (const float*)d_in[5];
    const float* l0_b2 = (const float*)d_in[6];
    const float* l0_Wres = (const float*)d_in[7];
    const float* Ws1 = (const float*)d_in[8];
    const float* bs1 = (const float*)d_in[9];
    const float* Ws2 = (const float*)d_in[10];
    const float* bs2 = (const float*)d_in[11];
    const float* fW1 = (const float*)d_in[12];
    const float* fb1 = (const float*)d_in[13];
    const float* fW2 = (const float*)d_in[14];
    const float* fb2 = (const float*)d_in[15];
    float* out = (float*)d_out;

    size_t used = 0;
    auto alloc = [&](size_t bytes) -> char* {
        char* r = (char*)d_ws + used;
        used = (used + bytes + 255) & ~(size_t)255;
        return r;
    };
    float* A = (float*)alloc((size_t)NN * HID * 4);
    float* B = (float*)alloc((size_t)NN * HID * 4);
    float* C = (float*)alloc((size_t)NN * HID * 4);
    int* bcur = (int*)alloc((size_t)NBK * 4);
    int* row_beg = (int*)alloc((size_t)NN * 4);
    int* row_end = (int*)alloc((size_t)NN * 4);
    int* esrc = (int*)alloc((size_t)NBK * BCAP * 4);
    // bedge (NBK*BCAP*4 = 4.0MB) aliases xb (NN*IND*2 = 6.4MB): bedge dead after build_csr
    char* shared_region = alloc((size_t)NN * IND * 2 > (size_t)NBK * BCAP * 4
                                    ? (size_t)NN * IND * 2
                                    : (size_t)NBK * BCAP * 4);
    unsigned int* bedge = (unsigned int*)shared_region;
    short* xb = (short*)shared_region;
    short* wresHi = (short*)alloc(128 * 64 * 2);
    short* wresLo = (short*)alloc(128 * 64 * 2);
    short* w1Hi = (short*)alloc(128 * 64 * 2);
    short* w1Lo = (short*)alloc(128 * 64 * 2);
    short* w2Hi = (short*)alloc(128 * 128 * 2);
    short* w2Lo = (short*)alloc(128 * 128 * 2);
    short* ws1Hi = (short*)alloc(3 * 128 * 128 * 2);
    short* ws1Lo = (short*)alloc(3 * 128 * 128 * 2);
    short* ws2Hi = (short*)alloc(3 * 128 * 128 * 2);
    short* ws2Lo = (short*)alloc(3 * 128 * 128 * 2);
    size_t needHb = (size_t)NN * HID * 2 + 256;
    bool useB = (used + needHb) <= ws_size;
    short* hb = nullptr;
    if (useB) hb = (short*)alloc((size_t)NN * HID * 2);

    hipMemsetAsync(bcur, 0, (size_t)NBK * 4, stream);

    const int GB = (NN + 63) / 64;
    const int AGGB = (NN + 3) / 4;

    convert_all<<<512, 256, 0, stream>>>(l0_Wres, l0_W1, l0_W2, Ws1, Ws2, wresHi, wresLo, w1Hi,
                                         w1Lo, w2Hi, w2Lo, ws1Hi, ws1Lo, ws2Hi, ws2Lo);

    // bucketed CSR build
    bin_kernel<<<(NE + 4095) / 4096, 256, 0, stream>>>(src, dst, bcur, bedge);
    build_csr_kernel<<<NBK, 256, 0, stream>>>(bedge, bcur, row_beg, row_end, esrc);

    // xb (aliases bedge -- safe after build_csr)
    if (useB) to_bf16_kernel<<<(NN * IND + 255) / 256, 256, 0, stream>>>(x, xb, NN * IND);

    // layer 0
    gemm_mfma<64, 0><<<GB, 256, 0, stream>>>(x, wresHi, wresLo, nullptr, nullptr, C, nullptr, NN);
    if (useB)
        agg64b_kernel<<<AGGB, 256, 0, stream>>>((const unsigned short*)xb, x, row_beg, row_end,
                                                esrc, A);
    else
        agg_kernel<64><<<AGGB, 256, 0, stream>>>(x, row_beg, row_end, esrc, A);
    gemm_mfma<64, 1><<<GB, 256, 0, stream>>>(A, w1Hi, w1Lo, l0_b1, nullptr, B, nullptr, NN);
    gemm_mfma<128, 2><<<GB, 256, 0, stream>>>(B, w2Hi, w2Lo, l0_b2, C, A, hb, NN);

    // layers 1..3
    float* hcur = A;
    float* tb = C;
    float* ub = B;
    for (int l = 0; l < 3; ++l) {
        if (useB)
            agg128b_kernel<<<AGGB, 256, 0, stream>>>((const unsigned int*)hb, hcur, row_beg,
                                                     row_end, esrc, tb);
        else
            agg_kernel<128><<<AGGB, 256, 0, stream>>>(hcur, row_beg, row_end, esrc, tb);
        gemm_mfma<128, 1><<<GB, 256, 0, stream>>>(tb, ws1Hi + (size_t)l * 16384,
                                                  ws1Lo + (size_t)l * 16384, bs1 + (size_t)l * HID,
                                                  nullptr, ub, nullptr, NN);
        gemm_mfma<128, 2><<<GB, 256, 0, stream>>>(ub, ws2Hi + (size_t)l * 16384,
                                                  ws2Lo + (size_t)l * 16384, bs2 + (size_t)l * HID,
                                                  hcur, tb, hb, NN);
        float* t2 = hcur;
        hcur = tb;
        tb = t2;
    }

    // fused mean-pool + head
    head_kernel<<<NG, 128, 0, stream>>>(hcur, batch, fW1, fb1, fW2, fb2, out);
}

// Round 7
// 560.122 us; speedup vs baseline: 1.4817x; 1.0916x over previous
//
#include <hip/hip_runtime.h>

#define NN 50000
#define NE 800000
#define IND 64
#define HID 128
#define NG 1024

#define NBK 391   // buckets of 128 dst nodes
#define BCAP 2560 // padded capacity per bucket (avg 2046, +11 sigma)

typedef short bf16x8 __attribute__((ext_vector_type(8)));
typedef float f32x4 __attribute__((ext_vector_type(4)));

static __device__ __forceinline__ unsigned short f2bf(float f) {
    unsigned int u = __float_as_uint(f);
    return (unsigned short)((u + 0x7FFFu + ((u >> 16) & 1u)) >> 16);
}
static __device__ __forceinline__ float bf2f(unsigned short h) {
    return __uint_as_float(((unsigned int)h) << 16);
}
static __device__ __forceinline__ float4 f4zero() { return make_float4(0.f, 0.f, 0.f, 0.f); }

// ---------------- bucketed CSR build ----------------
__global__ void bin_kernel(const int* __restrict__ src, const int* __restrict__ dst,
                           int* __restrict__ bcur, unsigned int* __restrict__ bedge) {
    __shared__ int hist[NBK];
    __shared__ int base[NBK];
    int tid = threadIdx.x;
    for (int i = tid; i < NBK; i += 256) hist[i] = 0;
    __syncthreads();
    int e0 = blockIdx.x * 4096;
    unsigned int pk[16];
    int bk[16], lo[16];
#pragma unroll
    for (int j = 0; j < 16; ++j) {
        int e = e0 + j * 256 + tid;
        bk[j] = -1;
        if (e < NE) {
            int s = src[e], d = dst[e];
            pk[j] = (unsigned int)s | ((unsigned int)d << 16);
            bk[j] = d >> 7;
            lo[j] = atomicAdd(&hist[bk[j]], 1);
        }
    }
    __syncthreads();
    for (int i = tid; i < NBK; i += 256)
        base[i] = hist[i] ? atomicAdd(&bcur[i], hist[i]) : 0;
    __syncthreads();
#pragma unroll
    for (int j = 0; j < 16; ++j) {
        if (bk[j] >= 0) {
            int idx = base[bk[j]] + lo[j];
            if (idx < BCAP) bedge[(size_t)bk[j] * BCAP + idx] = pk[j];
        }
    }
}

__global__ void build_csr_kernel(const unsigned int* __restrict__ bedge,
                                 const int* __restrict__ bcur, int* __restrict__ row_beg,
                                 int* __restrict__ row_end, int* __restrict__ esrc) {
    __shared__ unsigned int se[BCAP];
    __shared__ int h[128], sc[128], cur[128];
    int b = blockIdx.x, tid = threadIdx.x;
    int cnt = min(bcur[b], BCAP);
    for (int i = tid; i < cnt; i += 256) se[i] = bedge[(size_t)b * BCAP + i];
    if (tid < 128) h[tid] = 0;
    __syncthreads();
    for (int i = tid; i < cnt; i += 256) atomicAdd(&h[(se[i] >> 16) & 127], 1);
    __syncthreads();
    if (tid < 128) sc[tid] = h[tid];
    __syncthreads();
    for (int off = 1; off < 128; off <<= 1) {
        int add = 0;
        if (tid < 128 && tid >= off) add = sc[tid - off];
        __syncthreads();
        if (tid < 128) sc[tid] += add;
        __syncthreads();
    }
    if (tid < 128) {
        int ex = sc[tid] - h[tid];
        int n = (b << 7) + tid;
        if (n < NN) {
            row_beg[n] = b * BCAP + ex;
            row_end[n] = b * BCAP + sc[tid];
        }
        cur[tid] = ex;
    }
    __syncthreads();
    for (int i = tid; i < cnt; i += 256) {
        unsigned int v = se[i];
        int dl = (v >> 16) & 127;
        int pos = atomicAdd(&cur[dl], 1);
        esrc[(size_t)b * BCAP + pos] = (int)(v & 0xffffu);
    }
}

// ---------------- weight convert: W[K][128] fp32 -> Wt hi/lo [128][K] bf16 ----------------
__global__ void convert_all(const float* __restrict__ Wres, const float* __restrict__ W1,
                            const float* __restrict__ W2, const float* __restrict__ Ws1,
                            const float* __restrict__ Ws2, short* __restrict__ wresHi,
                            short* __restrict__ wresLo, short* __restrict__ w1Hi,
                            short* __restrict__ w1Lo, short* __restrict__ w2Hi,
                            short* __restrict__ w2Lo, short* __restrict__ ws1Hi,
                            short* __restrict__ ws1Lo, short* __restrict__ ws2Hi,
                            short* __restrict__ ws2Lo) {
    int t = blockIdx.x * 256 + threadIdx.x;
    const float* W;
    short *hi, *lo;
    int K, idx;
    if (t < 8192) { W = Wres; hi = wresHi; lo = wresLo; K = 64; idx = t; }
    else if (t < 16384) { W = W1; hi = w1Hi; lo = w1Lo; K = 64; idx = t - 8192; }
    else if (t < 32768) { W = W2; hi = w2Hi; lo = w2Lo; K = 128; idx = t - 16384; }
    else if (t < 81920) { W = Ws1; hi = ws1Hi; lo = ws1Lo; K = 128; idx = t - 32768; }
    else { W = Ws2; hi = ws2Hi; lo = ws2Lo; K = 128; idx = t - 81920; }
    int m = idx / (K * 128);
    int r = idx - m * K * 128;
    int n = r / K, k = r - n * K;
    float w = W[(size_t)m * K * 128 + k * 128 + n];
    unsigned short hh = f2bf(w);
    hi[idx] = (short)hh;
    lo[idx] = (short)f2bf(w - bf2f(hh));
}

__global__ void to_bf16_kernel(const float* __restrict__ s, short* __restrict__ d, int total) {
    int i = blockIdx.x * 256 + threadIdx.x;
    if (i < total) d[i] = (short)f2bf(s[i]);
}

// ---------------- bf16 gather aggregation, exact fp32 self term ----------------
__global__ void agg128b_kernel(const unsigned int* __restrict__ hb, const float* __restrict__ hf,
                               const int* __restrict__ row_beg, const int* __restrict__ row_end,
                               const int* __restrict__ es, float* __restrict__ t) {
    int wv = threadIdx.x >> 6, lane = threadIdx.x & 63;
    int n = blockIdx.x * 4 + wv;
    if (n >= NN) return;
    int beg = row_beg[n], end = row_end[n];
    float2 acc = ((const float2*)hf)[(size_t)n * 64 + lane];
    int e = beg;
    for (; e + 4 <= end; e += 4) {
        int s0 = es[e], s1 = es[e + 1], s2 = es[e + 2], s3 = es[e + 3];
        unsigned int v0 = hb[(size_t)s0 * 64 + lane];
        unsigned int v1 = hb[(size_t)s1 * 64 + lane];
        unsigned int v2 = hb[(size_t)s2 * 64 + lane];
        unsigned int v3 = hb[(size_t)s3 * 64 + lane];
        acc.x += __uint_as_float(v0 << 16) + __uint_as_float(v1 << 16) +
                 __uint_as_float(v2 << 16) + __uint_as_float(v3 << 16);
        acc.y += __uint_as_float(v0 & 0xffff0000u) + __uint_as_float(v1 & 0xffff0000u) +
                 __uint_as_float(v2 & 0xffff0000u) + __uint_as_float(v3 & 0xffff0000u);
    }
    for (; e < end; ++e) {
        unsigned int v = hb[(size_t)es[e] * 64 + lane];
        acc.x += __uint_as_float(v << 16);
        acc.y += __uint_as_float(v & 0xffff0000u);
    }
    ((float2*)t)[(size_t)n * 64 + lane] = acc;
}

__global__ void agg64b_kernel(const unsigned short* __restrict__ xb, const float* __restrict__ xf,
                              const int* __restrict__ row_beg, const int* __restrict__ row_end,
                              const int* __restrict__ es, float* __restrict__ t) {
    int wv = threadIdx.x >> 6, lane = threadIdx.x & 63;
    int n = blockIdx.x * 4 + wv;
    if (n >= NN) return;
    int beg = row_beg[n], end = row_end[n];
    float acc = xf[(size_t)n * 64 + lane];
    int e = beg;
    for (; e + 4 <= end; e += 4) {
        int s0 = es[e], s1 = es[e + 1], s2 = es[e + 2], s3 = es[e + 3];
        acc += bf2f(xb[(size_t)s0 * 64 + lane]) + bf2f(xb[(size_t)s1 * 64 + lane]) +
               bf2f(xb[(size_t)s2 * 64 + lane]) + bf2f(xb[(size_t)s3 * 64 + lane]);
    }
    for (; e < end; ++e) acc += bf2f(xb[(size_t)es[e] * 64 + lane]);
    t[(size_t)n * 64 + lane] = acc;
}

// ---------------- fused GIN layer: h = relu( relu(t@W1+b1)@W2 + b2 + res ) ----------------
// L0=1: KIN=64, res = x@Wres computed in-kernel (xres = x). L0=0: KIN=128, res = xres (global).
// 64 rows/block, 4 waves (wave wv owns rows wv*16..wv*16+15, all 128 cols).
// u never touches HBM: relu'd, split to bf16 hi/lo in LDS (same rounding as fp32-global path).
// Epilogue: acc -> swizzled LDS fp32 -> linear float4 writeout (coalesced h/hb/res traffic).
template <int L0>
__global__ __launch_bounds__(256, 4) void fused_layer(
    const float* __restrict__ tin, const float* __restrict__ xres,
    const short* __restrict__ W1Hi, const short* __restrict__ W1Lo,
    const float* __restrict__ b1, const short* __restrict__ W2Hi,
    const short* __restrict__ W2Lo, const float* __restrict__ b2,
    const short* __restrict__ WrHi, const short* __restrict__ WrLo,
    float* __restrict__ hout, short* __restrict__ hbout) {
    constexpr int KIN = L0 ? 64 : 128;
    constexpr int NKC1 = KIN / 32;
    __shared__ short lds[16384];  // 32 KB, reused across phases
    int tid = threadIdx.x;
    int rowBase = blockIdx.x * 64;
    int lane = tid & 63, wv = tid >> 6;
    int m = lane & 15, g = lane >> 4;

    // phase A: stage t tile (hi@0, lo@64*KIN); L0 also x tile (hi@8192, lo@12288)
    for (int i = tid; i < 64 * KIN / 4; i += 256) {
        int r = i / (KIN / 4), c4 = i - r * (KIN / 4);
        int row = rowBase + r;
        float4 v = f4zero();
        if (row < NN) v = ((const float4*)(tin + (size_t)row * KIN))[c4];
        unsigned short hx = f2bf(v.x), hy = f2bf(v.y), hz = f2bf(v.z), hw = f2bf(v.w);
        short4 hv = {(short)hx, (short)hy, (short)hz, (short)hw};
        short4 lv = {(short)f2bf(v.x - bf2f(hx)), (short)f2bf(v.y - bf2f(hy)),
                     (short)f2bf(v.z - bf2f(hz)), (short)f2bf(v.w - bf2f(hw))};
        int sidx = (r * KIN + c4 * 4) ^ ((r & 7) << 3);
        *(short4*)(lds + sidx) = hv;
        *(short4*)(lds + 64 * KIN + sidx) = lv;
    }
    if (L0) {
        for (int i = tid; i < 64 * 64 / 4; i += 256) {
            int r = i >> 4, c4 = i & 15;
            int row = rowBase + r;
            float4 v = f4zero();
            if (row < NN) v = ((const float4*)(xres + (size_t)row * 64))[c4];
            unsigned short hx = f2bf(v.x), hy = f2bf(v.y), hz = f2bf(v.z), hw = f2bf(v.w);
            short4 hv = {(short)hx, (short)hy, (short)hz, (short)hw};
            short4 lv = {(short)f2bf(v.x - bf2f(hx)), (short)f2bf(v.y - bf2f(hy)),
                         (short)f2bf(v.z - bf2f(hz)), (short)f2bf(v.w - bf2f(hw))};
            int sidx = (r * 64 + c4 * 4) ^ ((r & 7) << 3);
            *(short4*)(lds + 8192 + sidx) = hv;
            *(short4*)(lds + 12288 + sidx) = lv;
        }
    }
    __syncthreads();

    // preload A-fragments (t, and x for L0)
    int rloc = wv * 16 + m;
    bf16x8 tHi[NKC1], tLo[NKC1];
    bf16x8 xHi[2], xLo[2];
#pragma unroll
    for (int kc = 0; kc < NKC1; ++kc) {
        int idx = (rloc * KIN + kc * 32 + g * 8) ^ ((rloc & 7) << 3);
        tHi[kc] = *(const bf16x8*)(lds + idx);
        tLo[kc] = *(const bf16x8*)(lds + 64 * KIN + idx);
    }
    if (L0) {
#pragma unroll
        for (int kc = 0; kc < 2; ++kc) {
            int idx = (rloc * 64 + kc * 32 + g * 8) ^ ((rloc & 7) << 3);
            xHi[kc] = *(const bf16x8*)(lds + 8192 + idx);
            xLo[kc] = *(const bf16x8*)(lds + 12288 + idx);
        }
    }
    __syncthreads();  // all fragment reads done; LDS free for u

    f32x4 racc[8];
    // GEMM1: u = relu(t@W1+b1) -> LDS (hi@0, lo@8192); L0: racc = x@Wres
#pragma unroll
    for (int ct = 0; ct < 8; ++ct) {
        int col = ct * 16 + m;
        float bv = b1[col];
        f32x4 acc = {bv, bv, bv, bv};
#pragma unroll
        for (int kc = 0; kc < NKC1; ++kc) {
            bf16x8 bhi = *(const bf16x8*)(W1Hi + col * KIN + kc * 32 + g * 8);
            bf16x8 blo = *(const bf16x8*)(W1Lo + col * KIN + kc * 32 + g * 8);
            acc = __builtin_amdgcn_mfma_f32_16x16x32_bf16(tHi[kc], bhi, acc, 0, 0, 0);
            acc = __builtin_amdgcn_mfma_f32_16x16x32_bf16(tLo[kc], bhi, acc, 0, 0, 0);
            acc = __builtin_amdgcn_mfma_f32_16x16x32_bf16(tHi[kc], blo, acc, 0, 0, 0);
        }
        if (L0) {
            f32x4 r = {0.f, 0.f, 0.f, 0.f};
#pragma unroll
            for (int kc = 0; kc < 2; ++kc) {
                bf16x8 bhi = *(const bf16x8*)(WrHi + col * 64 + kc * 32 + g * 8);
                bf16x8 blo = *(const bf16x8*)(WrLo + col * 64 + kc * 32 + g * 8);
                r = __builtin_amdgcn_mfma_f32_16x16x32_bf16(xHi[kc], bhi, r, 0, 0, 0);
                r = __builtin_amdgcn_mfma_f32_16x16x32_bf16(xLo[kc], bhi, r, 0, 0, 0);
                r = __builtin_amdgcn_mfma_f32_16x16x32_bf16(xHi[kc], blo, r, 0, 0, 0);
            }
            racc[ct] = r;
        }
#pragma unroll
        for (int i = 0; i < 4; ++i) {
            float u = fmaxf(acc[i], 0.f);
            unsigned short uh = f2bf(u);
            int ru = wv * 16 + g * 4 + i;
            int sidx = (ru * 128 + col) ^ ((ru & 7) << 3);
            lds[sidx] = (short)uh;
            lds[8192 + sidx] = (short)f2bf(u - bf2f(uh));
        }
    }
    __syncthreads();

    // preload u fragments
    bf16x8 uHi[4], uLo[4];
#pragma unroll
    for (int kc = 0; kc < 4; ++kc) {
        int idx = (rloc * 128 + kc * 32 + g * 8) ^ ((rloc & 7) << 3);
        uHi[kc] = *(const bf16x8*)(lds + idx);
        uLo[kc] = *(const bf16x8*)(lds + 8192 + idx);
    }
    __syncthreads();  // LDS free for h

    float* fld = (float*)lds;  // [64][128] fp32, swizzled
    // GEMM2: acc2 = u@W2 + b2 (+racc, relu for L0) -> LDS
#pragma unroll
    for (int ct = 0; ct < 8; ++ct) {
        int col = ct * 16 + m;
        float bv = b2[col];
        f32x4 acc = {bv, bv, bv, bv};
#pragma unroll
        for (int kc = 0; kc < 4; ++kc) {
            bf16x8 bhi = *(const bf16x8*)(W2Hi + col * 128 + kc * 32 + g * 8);
            bf16x8 blo = *(const bf16x8*)(W2Lo + col * 128 + kc * 32 + g * 8);
            acc = __builtin_amdgcn_mfma_f32_16x16x32_bf16(uHi[kc], bhi, acc, 0, 0, 0);
            acc = __builtin_amdgcn_mfma_f32_16x16x32_bf16(uLo[kc], bhi, acc, 0, 0, 0);
            acc = __builtin_amdgcn_mfma_f32_16x16x32_bf16(uHi[kc], blo, acc, 0, 0, 0);
        }
#pragma unroll
        for (int i = 0; i < 4; ++i) {
            float v = acc[i];
            if (L0) v = fmaxf(v + racc[ct][i], 0.f);
            int ru = wv * 16 + g * 4 + i;
            int fidx = (ru * 128 + col) ^ ((ru & 7) << 3);
            fld[fidx] = v;
        }
    }
    __syncthreads();

    // coalesced writeout: float4 h, short4 hb (and float4 res read for layers 1..3)
    for (int i = tid; i < 2048; i += 256) {
        int r = i >> 5, c4 = i & 31;
        int row = rowBase + r;
        if (row >= NN) continue;
        int fidx = (r * 128 + c4 * 4) ^ ((r & 7) << 3);
        float4 v = *(const float4*)(fld + fidx);
        if (!L0) {
            float4 rs = ((const float4*)(xres + (size_t)row * 128))[c4];
            v.x = fmaxf(v.x + rs.x, 0.f);
            v.y = fmaxf(v.y + rs.y, 0.f);
            v.z = fmaxf(v.z + rs.z, 0.f);
            v.w = fmaxf(v.w + rs.w, 0.f);
        }
        ((float4*)(hout + (size_t)row * 128))[c4] = v;
        short4 bv4 = {(short)f2bf(v.x), (short)f2bf(v.y), (short)f2bf(v.z), (short)f2bf(v.w)};
        ((short4*)(hbout + (size_t)row * 128))[c4] = bv4;
    }
}

// ---------------- fused mean-pool + FC head ----------------
static __device__ __forceinline__ int lbound(const int* __restrict__ a, int n, int v) {
    int lo = 0, hi = n;
    while (lo < hi) {
        int mid = (lo + hi) >> 1;
        if (a[mid] < v) lo = mid + 1;
        else hi = mid;
    }
    return lo;
}

__global__ void head_kernel(const float* __restrict__ h, const int* __restrict__ batch,
                            const float* __restrict__ fW1, const float* __restrict__ fb1,
                            const float* __restrict__ fW2, const float* __restrict__ fb2,
                            float* __restrict__ out) {
    __shared__ float sp[128];
    __shared__ float su[128];
    __shared__ int sr[2];
    int g = blockIdx.x, t = threadIdx.x;
    if (t == 0) sr[0] = lbound(batch, NN, g);
    if (t == 1) sr[1] = lbound(batch, NN, g + 1);
    __syncthreads();
    int beg = sr[0], end = sr[1];
    float acc = 0.f;
    for (int i = beg; i < end; ++i) acc += h[(size_t)i * 128 + t];
    sp[t] = acc / (float)max(end - beg, 1);
    __syncthreads();
    float a = fb1[t];
#pragma unroll 4
    for (int k = 0; k < 128; ++k) a = fmaf(sp[k], fW1[k * 128 + t], a);
    a = a > 0.f ? a : 0.01f * a;
    su[t] = a * fW2[t];
    __syncthreads();
    for (int s2 = 64; s2 > 0; s2 >>= 1) {
        if (t < s2) su[t] += su[t + s2];
        __syncthreads();
    }
    if (t == 0) out[g] = su[0] + fb2[0];
}

extern "C" void kernel_launch(void* const* d_in, const int* in_sizes, int n_in,
                              void* d_out, int out_size, void* d_ws, size_t ws_size,
                              hipStream_t stream) {
    const float* x = (const float*)d_in[0];
    const int* eidx = (const int*)d_in[1];
    const int* src = eidx;
    const int* dst = eidx + NE;
    const int* batch = (const int*)d_in[2];
    const float* l0_W1 = (const float*)d_in[3];
    const float* l0_b1 = (const float*)d_in[4];
    const float* l0_W2 = (const float*)d_in[5];
    const float* l0_b2 = (const float*)d_in[6];
    const float* l0_Wres = (const float*)d_in[7];
    const float* Ws1 = (const float*)d_in[8];
    const float* bs1 = (const float*)d_in[9];
    const float* Ws2 = (const float*)d_in[10];
    const float* bs2 = (const float*)d_in[11];
    const float* fW1 = (const float*)d_in[12];
    const float* fb1 = (const float*)d_in[13];
    const float* fW2 = (const float*)d_in[14];
    const float* fb2 = (const float*)d_in[15];
    float* out = (float*)d_out;

    size_t used = 0;
    auto alloc = [&](size_t bytes) -> char* {
        char* r = (char*)d_ws + used;
        used = (used + bytes + 255) & ~(size_t)255;
        return r;
    };
    float* A = (float*)alloc((size_t)NN * HID * 4);  // t buffer
    float* B = (float*)alloc((size_t)NN * HID * 4);  // h ping
    float* C = (float*)alloc((size_t)NN * HID * 4);  // h pong
    int* bcur = (int*)alloc((size_t)NBK * 4);
    int* row_beg = (int*)alloc((size_t)NN * 4);
    int* row_end = (int*)alloc((size_t)NN * 4);
    int* esrc = (int*)alloc((size_t)NBK * BCAP * 4);
    // bedge (4.0MB) aliases xb (6.4MB): bedge dead after build_csr
    char* shared_region = alloc((size_t)NN * IND * 2 > (size_t)NBK * BCAP * 4
                                    ? (size_t)NN * IND * 2
                                    : (size_t)NBK * BCAP * 4);
    unsigned int* bedge = (unsigned int*)shared_region;
    short* xb = (short*)shared_region;
    short* wresHi = (short*)alloc(128 * 64 * 2);
    short* wresLo = (short*)alloc(128 * 64 * 2);
    short* w1Hi = (short*)alloc(128 * 64 * 2);
    short* w1Lo = (short*)alloc(128 * 64 * 2);
    short* w2Hi = (short*)alloc(128 * 128 * 2);
    short* w2Lo = (short*)alloc(128 * 128 * 2);
    short* ws1Hi = (short*)alloc(3 * 128 * 128 * 2);
    short* ws1Lo = (short*)alloc(3 * 128 * 128 * 2);
    short* ws2Hi = (short*)alloc(3 * 128 * 128 * 2);
    short* ws2Lo = (short*)alloc(3 * 128 * 128 * 2);
    short* hb = (short*)alloc((size_t)NN * HID * 2);

    hipMemsetAsync(bcur, 0, (size_t)NBK * 4, stream);

    const int GB = (NN + 63) / 64;   // 782
    const int AGGB = (NN + 3) / 4;   // 12500

    convert_all<<<512, 256, 0, stream>>>(l0_Wres, l0_W1, l0_W2, Ws1, Ws2, wresHi, wresLo, w1Hi,
                                         w1Lo, w2Hi, w2Lo, ws1Hi, ws1Lo, ws2Hi, ws2Lo);

    bin_kernel<<<(NE + 4095) / 4096, 256, 0, stream>>>(src, dst, bcur, bedge);
    build_csr_kernel<<<NBK, 256, 0, stream>>>(bedge, bcur, row_beg, row_end, esrc);

    to_bf16_kernel<<<(NN * IND + 255) / 256, 256, 0, stream>>>(x, xb, NN * IND);

    // layer 0: t0 = x + agg(x) -> A; h0 = fused(A, x) -> B (+ hb)
    agg64b_kernel<<<AGGB, 256, 0, stream>>>((const unsigned short*)xb, x, row_beg, row_end, esrc,
                                            A);
    fused_layer<1><<<GB, 256, 0, stream>>>(A, x, w1Hi, w1Lo, l0_b1, w2Hi, w2Lo, l0_b2, wresHi,
                                           wresLo, B, hb);

    // layers 1..3: t = h + agg(hb) -> A; h' = fused(A, h) -> ping-pong (+ hb)
    float* hcur = B;
    float* hnxt = C;
    for (int l = 0; l < 3; ++l) {
        agg128b_kernel<<<AGGB, 256, 0, stream>>>((const unsigned int*)hb, hcur, row_beg, row_end,
                                                 esrc, A);
        fused_layer<0><<<GB, 256, 0, stream>>>(A, hcur, ws1Hi + (size_t)l * 16384,
                                               ws1Lo + (size_t)l * 16384, bs1 + (size_t)l * HID,
                                               ws2Hi + (size_t)l * 16384,
                                               ws2Lo + (size_t)l * 16384, bs2 + (size_t)l * HID,
                                               nullptr, nullptr, hnxt, hb);
        float* t2 = hcur;
        hcur = hnxt;
        hnxt = t2;
    }

    head_kernel<<<NG, 128, 0, stream>>>(hcur, batch, fW1, fb1, fW2, fb2, out);
}

// Round 8
// 501.006 us; speedup vs baseline: 1.6565x; 1.1180x over previous
//
#include <hip/hip_runtime.h>

#define NN 50000
#define NE 800000
#define IND 64
#define HID 128
#define NG 1024

#define NBK 391   // buckets of 128 dst nodes
#define BCAP 2560 // padded capacity per bucket (avg 2046, +11 sigma)

typedef short bf16x8 __attribute__((ext_vector_type(8)));
typedef float f32x4 __attribute__((ext_vector_type(4)));

static __device__ __forceinline__ unsigned short f2bf(float f) {
    unsigned int u = __float_as_uint(f);
    return (unsigned short)((u + 0x7FFFu + ((u >> 16) & 1u)) >> 16);
}
static __device__ __forceinline__ float bf2f(unsigned short h) {
    return __uint_as_float(((unsigned int)h) << 16);
}
static __device__ __forceinline__ float4 f4zero() { return make_float4(0.f, 0.f, 0.f, 0.f); }

// ---------------- bucketed CSR build ----------------
__global__ void bin_kernel(const int* __restrict__ src, const int* __restrict__ dst,
                           int* __restrict__ bcur, unsigned int* __restrict__ bedge) {
    __shared__ int hist[NBK];
    __shared__ int base[NBK];
    int tid = threadIdx.x;
    for (int i = tid; i < NBK; i += 256) hist[i] = 0;
    __syncthreads();
    int e0 = blockIdx.x * 4096;
    unsigned int pk[16];
    int bk[16], lo[16];
#pragma unroll
    for (int j = 0; j < 16; ++j) {
        int e = e0 + j * 256 + tid;
        bk[j] = -1;
        if (e < NE) {
            int s = src[e], d = dst[e];
            pk[j] = (unsigned int)s | ((unsigned int)d << 16);
            bk[j] = d >> 7;
            lo[j] = atomicAdd(&hist[bk[j]], 1);
        }
    }
    __syncthreads();
    for (int i = tid; i < NBK; i += 256)
        base[i] = hist[i] ? atomicAdd(&bcur[i], hist[i]) : 0;
    __syncthreads();
#pragma unroll
    for (int j = 0; j < 16; ++j) {
        if (bk[j] >= 0) {
            int idx = base[bk[j]] + lo[j];
            if (idx < BCAP) bedge[(size_t)bk[j] * BCAP + idx] = pk[j];
        }
    }
}

__global__ void build_csr_kernel(const unsigned int* __restrict__ bedge,
                                 const int* __restrict__ bcur, int* __restrict__ row_beg,
                                 int* __restrict__ row_end, int* __restrict__ esrc) {
    __shared__ unsigned int se[BCAP];
    __shared__ int h[128], sc[128], cur[128];
    int b = blockIdx.x, tid = threadIdx.x;
    int cnt = min(bcur[b], BCAP);
    for (int i = tid; i < cnt; i += 256) se[i] = bedge[(size_t)b * BCAP + i];
    if (tid < 128) h[tid] = 0;
    __syncthreads();
    for (int i = tid; i < cnt; i += 256) atomicAdd(&h[(se[i] >> 16) & 127], 1);
    __syncthreads();
    if (tid < 128) sc[tid] = h[tid];
    __syncthreads();
    for (int off = 1; off < 128; off <<= 1) {
        int add = 0;
        if (tid < 128 && tid >= off) add = sc[tid - off];
        __syncthreads();
        if (tid < 128) sc[tid] += add;
        __syncthreads();
    }
    if (tid < 128) {
        int ex = sc[tid] - h[tid];
        int n = (b << 7) + tid;
        if (n < NN) {
            row_beg[n] = b * BCAP + ex;
            row_end[n] = b * BCAP + sc[tid];
        }
        cur[tid] = ex;
    }
    __syncthreads();
    for (int i = tid; i < cnt; i += 256) {
        unsigned int v = se[i];
        int dl = (v >> 16) & 127;
        int pos = atomicAdd(&cur[dl], 1);
        esrc[(size_t)b * BCAP + pos] = (int)(v & 0xffffu);
    }
}

// ---------------- weight convert: W[K][128] fp32 -> Wt hi/lo [128][K] bf16 ----------------
__global__ void convert_all(const float* __restrict__ Wres, const float* __restrict__ W1,
                            const float* __restrict__ W2, const float* __restrict__ Ws1,
                            const float* __restrict__ Ws2, short* __restrict__ wresHi,
                            short* __restrict__ wresLo, short* __restrict__ w1Hi,
                            short* __restrict__ w1Lo, short* __restrict__ w2Hi,
                            short* __restrict__ w2Lo, short* __restrict__ ws1Hi,
                            short* __restrict__ ws1Lo, short* __restrict__ ws2Hi,
                            short* __restrict__ ws2Lo) {
    int t = blockIdx.x * 256 + threadIdx.x;
    const float* W;
    short *hi, *lo;
    int K, idx;
    if (t < 8192) { W = Wres; hi = wresHi; lo = wresLo; K = 64; idx = t; }
    else if (t < 16384) { W = W1; hi = w1Hi; lo = w1Lo; K = 64; idx = t - 8192; }
    else if (t < 32768) { W = W2; hi = w2Hi; lo = w2Lo; K = 128; idx = t - 16384; }
    else if (t < 81920) { W = Ws1; hi = ws1Hi; lo = ws1Lo; K = 128; idx = t - 32768; }
    else { W = Ws2; hi = ws2Hi; lo = ws2Lo; K = 128; idx = t - 81920; }
    int m = idx / (K * 128);
    int r = idx - m * K * 128;
    int n = r / K, k = r - n * K;
    float w = W[(size_t)m * K * 128 + k * 128 + n];
    unsigned short hh = f2bf(w);
    hi[idx] = (short)hh;
    lo[idx] = (short)f2bf(w - bf2f(hh));
}

__global__ void to_bf16_kernel(const float* __restrict__ s, short* __restrict__ d, int total) {
    int i = blockIdx.x * 256 + threadIdx.x;
    if (i < total) d[i] = (short)f2bf(s[i]);
}

// ---------------- bf16 gather aggregation, exact fp32 self term ----------------
__global__ void agg128b_kernel(const unsigned int* __restrict__ hb, const float* __restrict__ hf,
                               const int* __restrict__ row_beg, const int* __restrict__ row_end,
                               const int* __restrict__ es, float* __restrict__ t) {
    int wv = threadIdx.x >> 6, lane = threadIdx.x & 63;
    int n = blockIdx.x * 4 + wv;
    if (n >= NN) return;
    int beg = row_beg[n], end = row_end[n];
    float2 acc = ((const float2*)hf)[(size_t)n * 64 + lane];
    int e = beg;
    for (; e + 4 <= end; e += 4) {
        int s0 = es[e], s1 = es[e + 1], s2 = es[e + 2], s3 = es[e + 3];
        unsigned int v0 = hb[(size_t)s0 * 64 + lane];
        unsigned int v1 = hb[(size_t)s1 * 64 + lane];
        unsigned int v2 = hb[(size_t)s2 * 64 + lane];
        unsigned int v3 = hb[(size_t)s3 * 64 + lane];
        acc.x += __uint_as_float(v0 << 16) + __uint_as_float(v1 << 16) +
                 __uint_as_float(v2 << 16) + __uint_as_float(v3 << 16);
        acc.y += __uint_as_float(v0 & 0xffff0000u) + __uint_as_float(v1 & 0xffff0000u) +
                 __uint_as_float(v2 & 0xffff0000u) + __uint_as_float(v3 & 0xffff0000u);
    }
    for (; e < end; ++e) {
        unsigned int v = hb[(size_t)es[e] * 64 + lane];
        acc.x += __uint_as_float(v << 16);
        acc.y += __uint_as_float(v & 0xffff0000u);
    }
    ((float2*)t)[(size_t)n * 64 + lane] = acc;
}

__global__ void agg64b_kernel(const unsigned short* __restrict__ xb, const float* __restrict__ xf,
                              const int* __restrict__ row_beg, const int* __restrict__ row_end,
                              const int* __restrict__ es, float* __restrict__ t) {
    int wv = threadIdx.x >> 6, lane = threadIdx.x & 63;
    int n = blockIdx.x * 4 + wv;
    if (n >= NN) return;
    int beg = row_beg[n], end = row_end[n];
    float acc = xf[(size_t)n * 64 + lane];
    int e = beg;
    for (; e + 4 <= end; e += 4) {
        int s0 = es[e], s1 = es[e + 1], s2 = es[e + 2], s3 = es[e + 3];
        acc += bf2f(xb[(size_t)s0 * 64 + lane]) + bf2f(xb[(size_t)s1 * 64 + lane]) +
               bf2f(xb[(size_t)s2 * 64 + lane]) + bf2f(xb[(size_t)s3 * 64 + lane]);
    }
    for (; e < end; ++e) acc += bf2f(xb[(size_t)es[e] * 64 + lane]);
    t[(size_t)n * 64 + lane] = acc;
}

// ---------------- weight-stationary fused GIN layer (K=128, layers 1..3) ----------------
// h = relu( relu(t@W1+b1)@W2 + b2 + res ). Wave wv owns cols wv*32..wv*32+31 (2 ct-tiles)
// across ALL 64 rows (4 subtiles). W1/W2 hi+lo frags resident in registers (128 VGPR) --
// zero global loads inside the MFMA loops. u round-trips through LDS (overwrites t staging).
// Epilogue stores directly from acc (16 m-lanes = one 64B line, coalesced).
__global__ __launch_bounds__(256, 2) void fused_layer_ws(
    const float* __restrict__ tin, const float* __restrict__ xres,
    const short* __restrict__ W1Hi, const short* __restrict__ W1Lo,
    const float* __restrict__ b1, const short* __restrict__ W2Hi,
    const short* __restrict__ W2Lo, const float* __restrict__ b2,
    float* __restrict__ hout, short* __restrict__ hbout) {
    __shared__ short lds[16384];  // hi @ [0..8191], lo @ [8192..16383] (shorts)
    int tid = threadIdx.x;
    int rowBase = blockIdx.x * 64;
    int lane = tid & 63, wv = tid >> 6;
    int m = lane & 15, g = lane >> 4;

    // preload W fragments (32 x 16B loads, issued before staging; L2-resident)
    bf16x8 w1h[2][4], w1l[2][4], w2h[2][4], w2l[2][4];
#pragma unroll
    for (int ctl = 0; ctl < 2; ++ctl) {
        int col = wv * 32 + ctl * 16 + m;
#pragma unroll
        for (int kc = 0; kc < 4; ++kc) {
            int off = col * 128 + kc * 32 + g * 8;
            w1h[ctl][kc] = *(const bf16x8*)(W1Hi + off);
            w1l[ctl][kc] = *(const bf16x8*)(W1Lo + off);
            w2h[ctl][kc] = *(const bf16x8*)(W2Hi + off);
            w2l[ctl][kc] = *(const bf16x8*)(W2Lo + off);
        }
    }

    // stage t tile [64][128] -> hi/lo, swizzled
    for (int i = tid; i < 2048; i += 256) {
        int r = i >> 5, c4 = i & 31;
        int row = rowBase + r;
        float4 v = f4zero();
        if (row < NN) v = ((const float4*)(tin + (size_t)row * 128))[c4];
        unsigned short hx = f2bf(v.x), hy = f2bf(v.y), hz = f2bf(v.z), hw = f2bf(v.w);
        short4 hv = {(short)hx, (short)hy, (short)hz, (short)hw};
        short4 lv = {(short)f2bf(v.x - bf2f(hx)), (short)f2bf(v.y - bf2f(hy)),
                     (short)f2bf(v.z - bf2f(hz)), (short)f2bf(v.w - bf2f(hw))};
        int sidx = (r * 128 + c4 * 4) ^ ((r & 7) << 3);
        *(short4*)(lds + sidx) = hv;
        *(short4*)(lds + 8192 + sidx) = lv;
    }
    __syncthreads();

    // GEMM1: acc1[s][ctl] for all 4 row-subtiles (A-frags from LDS, W from registers)
    f32x4 acc1[4][2];
#pragma unroll
    for (int s = 0; s < 4; ++s) {
        int rloc = s * 16 + m;
        bf16x8 tHi[4], tLo[4];
#pragma unroll
        for (int kc = 0; kc < 4; ++kc) {
            int idx = (rloc * 128 + kc * 32 + g * 8) ^ ((rloc & 7) << 3);
            tHi[kc] = *(const bf16x8*)(lds + idx);
            tLo[kc] = *(const bf16x8*)(lds + 8192 + idx);
        }
#pragma unroll
        for (int ctl = 0; ctl < 2; ++ctl) {
            float bv = b1[wv * 32 + ctl * 16 + m];
            f32x4 a = {bv, bv, bv, bv};
#pragma unroll
            for (int kc = 0; kc < 4; ++kc) {
                a = __builtin_amdgcn_mfma_f32_16x16x32_bf16(tHi[kc], w1h[ctl][kc], a, 0, 0, 0);
                a = __builtin_amdgcn_mfma_f32_16x16x32_bf16(tLo[kc], w1h[ctl][kc], a, 0, 0, 0);
                a = __builtin_amdgcn_mfma_f32_16x16x32_bf16(tHi[kc], w1l[ctl][kc], a, 0, 0, 0);
            }
            acc1[s][ctl] = a;
        }
    }
    __syncthreads();  // all t reads done; LDS free for u

    // u = relu(acc1) -> LDS hi/lo (same layout/swizzle as t)
#pragma unroll
    for (int s = 0; s < 4; ++s) {
#pragma unroll
        for (int ctl = 0; ctl < 2; ++ctl) {
            int col = wv * 32 + ctl * 16 + m;
#pragma unroll
            for (int i = 0; i < 4; ++i) {
                float u = fmaxf(acc1[s][ctl][i], 0.f);
                unsigned short uh = f2bf(u);
                int ru = s * 16 + g * 4 + i;
                int sidx = (ru * 128 + col) ^ ((ru & 7) << 3);
                lds[sidx] = (short)uh;
                lds[8192 + sidx] = (short)f2bf(u - bf2f(uh));
            }
        }
    }
    __syncthreads();

    // GEMM2 + direct epilogue (res add + relu + h/hb stores)
#pragma unroll
    for (int s = 0; s < 4; ++s) {
        int rloc = s * 16 + m;
        bf16x8 uHi[4], uLo[4];
#pragma unroll
        for (int kc = 0; kc < 4; ++kc) {
            int idx = (rloc * 128 + kc * 32 + g * 8) ^ ((rloc & 7) << 3);
            uHi[kc] = *(const bf16x8*)(lds + idx);
            uLo[kc] = *(const bf16x8*)(lds + 8192 + idx);
        }
#pragma unroll
        for (int ctl = 0; ctl < 2; ++ctl) {
            int col = wv * 32 + ctl * 16 + m;
            float bv = b2[col];
            f32x4 a = {bv, bv, bv, bv};
#pragma unroll
            for (int kc = 0; kc < 4; ++kc) {
                a = __builtin_amdgcn_mfma_f32_16x16x32_bf16(uHi[kc], w2h[ctl][kc], a, 0, 0, 0);
                a = __builtin_amdgcn_mfma_f32_16x16x32_bf16(uLo[kc], w2h[ctl][kc], a, 0, 0, 0);
                a = __builtin_amdgcn_mfma_f32_16x16x32_bf16(uHi[kc], w2l[ctl][kc], a, 0, 0, 0);
            }
#pragma unroll
            for (int i = 0; i < 4; ++i) {
                int row = rowBase + s * 16 + g * 4 + i;
                if (row < NN) {
                    float v = fmaxf(a[i] + xres[(size_t)row * 128 + col], 0.f);
                    hout[(size_t)row * 128 + col] = v;
                    hbout[(size_t)row * 128 + col] = (short)f2bf(v);
                }
            }
        }
    }
}

// ---------------- fused GIN layer 0 (round-7 structure, K=64, Wres in-kernel) ----------------
template <int L0>
__global__ __launch_bounds__(256, 4) void fused_layer(
    const float* __restrict__ tin, const float* __restrict__ xres,
    const short* __restrict__ W1Hi, const short* __restrict__ W1Lo,
    const float* __restrict__ b1, const short* __restrict__ W2Hi,
    const short* __restrict__ W2Lo, const float* __restrict__ b2,
    const short* __restrict__ WrHi, const short* __restrict__ WrLo,
    float* __restrict__ hout, short* __restrict__ hbout) {
    constexpr int KIN = L0 ? 64 : 128;
    constexpr int NKC1 = KIN / 32;
    __shared__ short lds[16384];
    int tid = threadIdx.x;
    int rowBase = blockIdx.x * 64;
    int lane = tid & 63, wv = tid >> 6;
    int m = lane & 15, g = lane >> 4;

    for (int i = tid; i < 64 * KIN / 4; i += 256) {
        int r = i / (KIN / 4), c4 = i - r * (KIN / 4);
        int row = rowBase + r;
        float4 v = f4zero();
        if (row < NN) v = ((const float4*)(tin + (size_t)row * KIN))[c4];
        unsigned short hx = f2bf(v.x), hy = f2bf(v.y), hz = f2bf(v.z), hw = f2bf(v.w);
        short4 hv = {(short)hx, (short)hy, (short)hz, (short)hw};
        short4 lv = {(short)f2bf(v.x - bf2f(hx)), (short)f2bf(v.y - bf2f(hy)),
                     (short)f2bf(v.z - bf2f(hz)), (short)f2bf(v.w - bf2f(hw))};
        int sidx = (r * KIN + c4 * 4) ^ ((r & 7) << 3);
        *(short4*)(lds + sidx) = hv;
        *(short4*)(lds + 64 * KIN + sidx) = lv;
    }
    if (L0) {
        for (int i = tid; i < 64 * 64 / 4; i += 256) {
            int r = i >> 4, c4 = i & 15;
            int row = rowBase + r;
            float4 v = f4zero();
            if (row < NN) v = ((const float4*)(xres + (size_t)row * 64))[c4];
            unsigned short hx = f2bf(v.x), hy = f2bf(v.y), hz = f2bf(v.z), hw = f2bf(v.w);
            short4 hv = {(short)hx, (short)hy, (short)hz, (short)hw};
            short4 lv = {(short)f2bf(v.x - bf2f(hx)), (short)f2bf(v.y - bf2f(hy)),
                         (short)f2bf(v.z - bf2f(hz)), (short)f2bf(v.w - bf2f(hw))};
            int sidx = (r * 64 + c4 * 4) ^ ((r & 7) << 3);
            *(short4*)(lds + 8192 + sidx) = hv;
            *(short4*)(lds + 12288 + sidx) = lv;
        }
    }
    __syncthreads();

    int rloc = wv * 16 + m;
    bf16x8 tHi[NKC1], tLo[NKC1];
    bf16x8 xHi[2], xLo[2];
#pragma unroll
    for (int kc = 0; kc < NKC1; ++kc) {
        int idx = (rloc * KIN + kc * 32 + g * 8) ^ ((rloc & 7) << 3);
        tHi[kc] = *(const bf16x8*)(lds + idx);
        tLo[kc] = *(const bf16x8*)(lds + 64 * KIN + idx);
    }
    if (L0) {
#pragma unroll
        for (int kc = 0; kc < 2; ++kc) {
            int idx = (rloc * 64 + kc * 32 + g * 8) ^ ((rloc & 7) << 3);
            xHi[kc] = *(const bf16x8*)(lds + 8192 + idx);
            xLo[kc] = *(const bf16x8*)(lds + 12288 + idx);
        }
    }
    __syncthreads();

    f32x4 racc[8];
#pragma unroll
    for (int ct = 0; ct < 8; ++ct) {
        int col = ct * 16 + m;
        float bv = b1[col];
        f32x4 acc = {bv, bv, bv, bv};
#pragma unroll
        for (int kc = 0; kc < NKC1; ++kc) {
            bf16x8 bhi = *(const bf16x8*)(W1Hi + col * KIN + kc * 32 + g * 8);
            bf16x8 blo = *(const bf16x8*)(W1Lo + col * KIN + kc * 32 + g * 8);
            acc = __builtin_amdgcn_mfma_f32_16x16x32_bf16(tHi[kc], bhi, acc, 0, 0, 0);
            acc = __builtin_amdgcn_mfma_f32_16x16x32_bf16(tLo[kc], bhi, acc, 0, 0, 0);
            acc = __builtin_amdgcn_mfma_f32_16x16x32_bf16(tHi[kc], blo, acc, 0, 0, 0);
        }
        if (L0) {
            f32x4 r = {0.f, 0.f, 0.f, 0.f};
#pragma unroll
            for (int kc = 0; kc < 2; ++kc) {
                bf16x8 bhi = *(const bf16x8*)(WrHi + col * 64 + kc * 32 + g * 8);
                bf16x8 blo = *(const bf16x8*)(WrLo + col * 64 + kc * 32 + g * 8);
                r = __builtin_amdgcn_mfma_f32_16x16x32_bf16(xHi[kc], bhi, r, 0, 0, 0);
                r = __builtin_amdgcn_mfma_f32_16x16x32_bf16(xLo[kc], bhi, r, 0, 0, 0);
                r = __builtin_amdgcn_mfma_f32_16x16x32_bf16(xHi[kc], blo, r, 0, 0, 0);
            }
            racc[ct] = r;
        }
#pragma unroll
        for (int i = 0; i < 4; ++i) {
            float u = fmaxf(acc[i], 0.f);
            unsigned short uh = f2bf(u);
            int ru = wv * 16 + g * 4 + i;
            int sidx = (ru * 128 + col) ^ ((ru & 7) << 3);
            lds[sidx] = (short)uh;
            lds[8192 + sidx] = (short)f2bf(u - bf2f(uh));
        }
    }
    __syncthreads();

    bf16x8 uHi[4], uLo[4];
#pragma unroll
    for (int kc = 0; kc < 4; ++kc) {
        int idx = (rloc * 128 + kc * 32 + g * 8) ^ ((rloc & 7) << 3);
        uHi[kc] = *(const bf16x8*)(lds + idx);
        uLo[kc] = *(const bf16x8*)(lds + 8192 + idx);
    }
    __syncthreads();

    float* fld = (float*)lds;
#pragma unroll
    for (int ct = 0; ct < 8; ++ct) {
        int col = ct * 16 + m;
        float bv = b2[col];
        f32x4 acc = {bv, bv, bv, bv};
#pragma unroll
        for (int kc = 0; kc < 4; ++kc) {
            bf16x8 bhi = *(const bf16x8*)(W2Hi + col * 128 + kc * 32 + g * 8);
            bf16x8 blo = *(const bf16x8*)(W2Lo + col * 128 + kc * 32 + g * 8);
            acc = __builtin_amdgcn_mfma_f32_16x16x32_bf16(uHi[kc], bhi, acc, 0, 0, 0);
            acc = __builtin_amdgcn_mfma_f32_16x16x32_bf16(uLo[kc], bhi, acc, 0, 0, 0);
            acc = __builtin_amdgcn_mfma_f32_16x16x32_bf16(uHi[kc], blo, acc, 0, 0, 0);
        }
#pragma unroll
        for (int i = 0; i < 4; ++i) {
            float v = acc[i];
            if (L0) v = fmaxf(v + racc[ct][i], 0.f);
            int ru = wv * 16 + g * 4 + i;
            int fidx = (ru * 128 + col) ^ ((ru & 7) << 3);
            fld[fidx] = v;
        }
    }
    __syncthreads();

    for (int i = tid; i < 2048; i += 256) {
        int r = i >> 5, c4 = i & 31;
        int row = rowBase + r;
        if (row >= NN) continue;
        int fidx = (r * 128 + c4 * 4) ^ ((r & 7) << 3);
        float4 v = *(const float4*)(fld + fidx);
        if (!L0) {
            float4 rs = ((const float4*)(xres + (size_t)row * 128))[c4];
            v.x = fmaxf(v.x + rs.x, 0.f);
            v.y = fmaxf(v.y + rs.y, 0.f);
            v.z = fmaxf(v.z + rs.z, 0.f);
            v.w = fmaxf(v.w + rs.w, 0.f);
        }
        ((float4*)(hout + (size_t)row * 128))[c4] = v;
        short4 bv4 = {(short)f2bf(v.x), (short)f2bf(v.y), (short)f2bf(v.z), (short)f2bf(v.w)};
        ((short4*)(hbout + (size_t)row * 128))[c4] = bv4;
    }
}

// ---------------- fused mean-pool + FC head ----------------
static __device__ __forceinline__ int lbound(const int* __restrict__ a, int n, int v) {
    int lo = 0, hi = n;
    while (lo < hi) {
        int mid = (lo + hi) >> 1;
        if (a[mid] < v) lo = mid + 1;
        else hi = mid;
    }
    return lo;
}

__global__ void head_kernel(const float* __restrict__ h, const int* __restrict__ batch,
                            const float* __restrict__ fW1, const float* __restrict__ fb1,
                            const float* __restrict__ fW2, const float* __restrict__ fb2,
                            float* __restrict__ out) {
    __shared__ float sp[128];
    __shared__ float su[128];
    __shared__ int sr[2];
    int g = blockIdx.x, t = threadIdx.x;
    if (t == 0) sr[0] = lbound(batch, NN, g);
    if (t == 1) sr[1] = lbound(batch, NN, g + 1);
    __syncthreads();
    int beg = sr[0], end = sr[1];
    float acc = 0.f;
    for (int i = beg; i < end; ++i) acc += h[(size_t)i * 128 + t];
    sp[t] = acc / (float)max(end - beg, 1);
    __syncthreads();
    float a = fb1[t];
#pragma unroll 4
    for (int k = 0; k < 128; ++k) a = fmaf(sp[k], fW1[k * 128 + t], a);
    a = a > 0.f ? a : 0.01f * a;
    su[t] = a * fW2[t];
    __syncthreads();
    for (int s2 = 64; s2 > 0; s2 >>= 1) {
        if (t < s2) su[t] += su[t + s2];
        __syncthreads();
    }
    if (t == 0) out[g] = su[0] + fb2[0];
}

extern "C" void kernel_launch(void* const* d_in, const int* in_sizes, int n_in,
                              void* d_out, int out_size, void* d_ws, size_t ws_size,
                              hipStream_t stream) {
    const float* x = (const float*)d_in[0];
    const int* eidx = (const int*)d_in[1];
    const int* src = eidx;
    const int* dst = eidx + NE;
    const int* batch = (const int*)d_in[2];
    const float* l0_W1 = (const float*)d_in[3];
    const float* l0_b1 = (const float*)d_in[4];
    const float* l0_W2 = (const float*)d_in[5];
    const float* l0_b2 = (const float*)d_in[6];
    const float* l0_Wres = (const float*)d_in[7];
    const float* Ws1 = (const float*)d_in[8];
    const float* bs1 = (const float*)d_in[9];
    const float* Ws2 = (const float*)d_in[10];
    const float* bs2 = (const float*)d_in[11];
    const float* fW1 = (const float*)d_in[12];
    const float* fb1 = (const float*)d_in[13];
    const float* fW2 = (const float*)d_in[14];
    const float* fb2 = (const float*)d_in[15];
    float* out = (float*)d_out;

    size_t used = 0;
    auto alloc = [&](size_t bytes) -> char* {
        char* r = (char*)d_ws + used;
        used = (used + bytes + 255) & ~(size_t)255;
        return r;
    };
    float* A = (float*)alloc((size_t)NN * HID * 4);  // t buffer
    float* B = (float*)alloc((size_t)NN * HID * 4);  // h ping
    float* C = (float*)alloc((size_t)NN * HID * 4);  // h pong
    int* bcur = (int*)alloc((size_t)NBK * 4);
    int* row_beg = (int*)alloc((size_t)NN * 4);
    int* row_end = (int*)alloc((size_t)NN * 4);
    int* esrc = (int*)alloc((size_t)NBK * BCAP * 4);
    // bedge (4.0MB) aliases xb (6.4MB): bedge dead after build_csr
    char* shared_region = alloc((size_t)NN * IND * 2 > (size_t)NBK * BCAP * 4
                                    ? (size_t)NN * IND * 2
                                    : (size_t)NBK * BCAP * 4);
    unsigned int* bedge = (unsigned int*)shared_region;
    short* xb = (short*)shared_region;
    short* wresHi = (short*)alloc(128 * 64 * 2);
    short* wresLo = (short*)alloc(128 * 64 * 2);
    short* w1Hi = (short*)alloc(128 * 64 * 2);
    short* w1Lo = (short*)alloc(128 * 64 * 2);
    short* w2Hi = (short*)alloc(128 * 128 * 2);
    short* w2Lo = (short*)alloc(128 * 128 * 2);
    short* ws1Hi = (short*)alloc(3 * 128 * 128 * 2);
    short* ws1Lo = (short*)alloc(3 * 128 * 128 * 2);
    short* ws2Hi = (short*)alloc(3 * 128 * 128 * 2);
    short* ws2Lo = (short*)alloc(3 * 128 * 128 * 2);
    short* hb = (short*)alloc((size_t)NN * HID * 2);

    hipMemsetAsync(bcur, 0, (size_t)NBK * 4, stream);

    const int GB = (NN + 63) / 64;   // 782
    const int AGGB = (NN + 3) / 4;   // 12500

    convert_all<<<512, 256, 0, stream>>>(l0_Wres, l0_W1, l0_W2, Ws1, Ws2, wresHi, wresLo, w1Hi,
                                         w1Lo, w2Hi, w2Lo, ws1Hi, ws1Lo, ws2Hi, ws2Lo);

    bin_kernel<<<(NE + 4095) / 4096, 256, 0, stream>>>(src, dst, bcur, bedge);
    build_csr_kernel<<<NBK, 256, 0, stream>>>(bedge, bcur, row_beg, row_end, esrc);

    to_bf16_kernel<<<(NN * IND + 255) / 256, 256, 0, stream>>>(x, xb, NN * IND);

    // layer 0: t0 = x + agg(x) -> A; h0 = fused(A, x) -> B (+ hb)
    agg64b_kernel<<<AGGB, 256, 0, stream>>>((const unsigned short*)xb, x, row_beg, row_end, esrc,
                                            A);
    fused_layer<1><<<GB, 256, 0, stream>>>(A, x, w1Hi, w1Lo, l0_b1, w2Hi, w2Lo, l0_b2, wresHi,
                                           wresLo, B, hb);

    // layers 1..3: t = h + agg(hb) -> A; h' = fused_ws(A, h) -> ping-pong (+ hb)
    float* hcur = B;
    float* hnxt = C;
    for (int l = 0; l < 3; ++l) {
        agg128b_kernel<<<AGGB, 256, 0, stream>>>((const unsigned int*)hb, hcur, row_beg, row_end,
                                                 esrc, A);
        fused_layer_ws<<<GB, 256, 0, stream>>>(A, hcur, ws1Hi + (size_t)l * 16384,
                                               ws1Lo + (size_t)l * 16384, bs1 + (size_t)l * HID,
                                               ws2Hi + (size_t)l * 16384,
                                               ws2Lo + (size_t)l * 16384, bs2 + (size_t)l * HID,
                                               hnxt, hb);
        float* t2 = hcur;
        hcur = hnxt;
        hnxt = t2;
    }

    head_kernel<<<NG, 128, 0, stream>>>(hcur, batch, fW1, fb1, fW2, fb2, out);
}

// Round 9
// 469.355 us; speedup vs baseline: 1.7682x; 1.0674x over previous
//
#include <hip/hip_runtime.h>

#define NN 50000
#define NE 800000
#define IND 64
#define HID 128
#define NG 1024

#define NBK 391   // buckets of 128 dst nodes
#define BCAP 2560 // padded capacity per bucket (avg 2046, +11 sigma)

typedef short bf16x8 __attribute__((ext_vector_type(8)));
typedef float f32x4 __attribute__((ext_vector_type(4)));

static __device__ __forceinline__ unsigned short f2bf(float f) {
    unsigned int u = __float_as_uint(f);
    return (unsigned short)((u + 0x7FFFu + ((u >> 16) & 1u)) >> 16);
}
static __device__ __forceinline__ float bf2f(unsigned short h) {
    return __uint_as_float(((unsigned int)h) << 16);
}
static __device__ __forceinline__ float4 f4zero() { return make_float4(0.f, 0.f, 0.f, 0.f); }

// ---------------- bucketed CSR build ----------------
__global__ void bin_kernel(const int* __restrict__ src, const int* __restrict__ dst,
                           int* __restrict__ bcur, unsigned int* __restrict__ bedge) {
    __shared__ int hist[NBK];
    __shared__ int base[NBK];
    int tid = threadIdx.x;
    for (int i = tid; i < NBK; i += 256) hist[i] = 0;
    __syncthreads();
    int e0 = blockIdx.x * 4096;
    unsigned int pk[16];
    int bk[16], lo[16];
#pragma unroll
    for (int j = 0; j < 16; ++j) {
        int e = e0 + j * 256 + tid;
        bk[j] = -1;
        if (e < NE) {
            int s = src[e], d = dst[e];
            pk[j] = (unsigned int)s | ((unsigned int)d << 16);
            bk[j] = d >> 7;
            lo[j] = atomicAdd(&hist[bk[j]], 1);
        }
    }
    __syncthreads();
    for (int i = tid; i < NBK; i += 256)
        base[i] = hist[i] ? atomicAdd(&bcur[i], hist[i]) : 0;
    __syncthreads();
#pragma unroll
    for (int j = 0; j < 16; ++j) {
        if (bk[j] >= 0) {
            int idx = base[bk[j]] + lo[j];
            if (idx < BCAP) bedge[(size_t)bk[j] * BCAP + idx] = pk[j];
        }
    }
}

__global__ void build_csr_kernel(const unsigned int* __restrict__ bedge,
                                 const int* __restrict__ bcur, int* __restrict__ row_beg,
                                 int* __restrict__ row_end, int* __restrict__ esrc) {
    __shared__ unsigned int se[BCAP];
    __shared__ int h[128], sc[128], cur[128];
    int b = blockIdx.x, tid = threadIdx.x;
    int cnt = min(bcur[b], BCAP);
    for (int i = tid; i < cnt; i += 256) se[i] = bedge[(size_t)b * BCAP + i];
    if (tid < 128) h[tid] = 0;
    __syncthreads();
    for (int i = tid; i < cnt; i += 256) atomicAdd(&h[(se[i] >> 16) & 127], 1);
    __syncthreads();
    if (tid < 128) sc[tid] = h[tid];
    __syncthreads();
    for (int off = 1; off < 128; off <<= 1) {
        int add = 0;
        if (tid < 128 && tid >= off) add = sc[tid - off];
        __syncthreads();
        if (tid < 128) sc[tid] += add;
        __syncthreads();
    }
    if (tid < 128) {
        int ex = sc[tid] - h[tid];
        int n = (b << 7) + tid;
        if (n < NN) {
            row_beg[n] = b * BCAP + ex;
            row_end[n] = b * BCAP + sc[tid];
        }
        cur[tid] = ex;
    }
    __syncthreads();
    for (int i = tid; i < cnt; i += 256) {
        unsigned int v = se[i];
        int dl = (v >> 16) & 127;
        int pos = atomicAdd(&cur[dl], 1);
        esrc[(size_t)b * BCAP + pos] = (int)(v & 0xffffu);
    }
}

// ---------------- weight convert: W[K][128] fp32 -> Wt hi/lo [128][K] bf16 ----------------
__global__ void convert_all(const float* __restrict__ Wres, const float* __restrict__ W1,
                            const float* __restrict__ W2, const float* __restrict__ Ws1,
                            const float* __restrict__ Ws2, short* __restrict__ wresHi,
                            short* __restrict__ wresLo, short* __restrict__ w1Hi,
                            short* __restrict__ w1Lo, short* __restrict__ w2Hi,
                            short* __restrict__ w2Lo, short* __restrict__ ws1Hi,
                            short* __restrict__ ws1Lo, short* __restrict__ ws2Hi,
                            short* __restrict__ ws2Lo) {
    int t = blockIdx.x * 256 + threadIdx.x;
    const float* W;
    short *hi, *lo;
    int K, idx;
    if (t < 8192) { W = Wres; hi = wresHi; lo = wresLo; K = 64; idx = t; }
    else if (t < 16384) { W = W1; hi = w1Hi; lo = w1Lo; K = 64; idx = t - 8192; }
    else if (t < 32768) { W = W2; hi = w2Hi; lo = w2Lo; K = 128; idx = t - 16384; }
    else if (t < 81920) { W = Ws1; hi = ws1Hi; lo = ws1Lo; K = 128; idx = t - 32768; }
    else { W = Ws2; hi = ws2Hi; lo = ws2Lo; K = 128; idx = t - 81920; }
    int m = idx / (K * 128);
    int r = idx - m * K * 128;
    int n = r / K, k = r - n * K;
    float w = W[(size_t)m * K * 128 + k * 128 + n];
    unsigned short hh = f2bf(w);
    hi[idx] = (short)hh;
    lo[idx] = (short)f2bf(w - bf2f(hh));
}

__global__ void to_bf16_kernel(const float* __restrict__ s, short* __restrict__ d, int total) {
    int i = blockIdx.x * 256 + threadIdx.x;
    if (i < total) d[i] = (short)f2bf(s[i]);
}

// ---------------- bf16 gather aggregation, exact fp32 self term ----------------
__global__ void agg128b_kernel(const unsigned int* __restrict__ hb, const float* __restrict__ hf,
                               const int* __restrict__ row_beg, const int* __restrict__ row_end,
                               const int* __restrict__ es, float* __restrict__ t) {
    int wv = threadIdx.x >> 6, lane = threadIdx.x & 63;
    int n = blockIdx.x * 4 + wv;
    if (n >= NN) return;
    int beg = row_beg[n], end = row_end[n];
    float2 acc = ((const float2*)hf)[(size_t)n * 64 + lane];
    int e = beg;
    for (; e + 8 <= end; e += 8) {
        unsigned int v0 = hb[(size_t)es[e] * 64 + lane];
        unsigned int v1 = hb[(size_t)es[e + 1] * 64 + lane];
        unsigned int v2 = hb[(size_t)es[e + 2] * 64 + lane];
        unsigned int v3 = hb[(size_t)es[e + 3] * 64 + lane];
        unsigned int v4 = hb[(size_t)es[e + 4] * 64 + lane];
        unsigned int v5 = hb[(size_t)es[e + 5] * 64 + lane];
        unsigned int v6 = hb[(size_t)es[e + 6] * 64 + lane];
        unsigned int v7 = hb[(size_t)es[e + 7] * 64 + lane];
        acc.x += __uint_as_float(v0 << 16) + __uint_as_float(v1 << 16) +
                 __uint_as_float(v2 << 16) + __uint_as_float(v3 << 16) +
                 __uint_as_float(v4 << 16) + __uint_as_float(v5 << 16) +
                 __uint_as_float(v6 << 16) + __uint_as_float(v7 << 16);
        acc.y += __uint_as_float(v0 & 0xffff0000u) + __uint_as_float(v1 & 0xffff0000u) +
                 __uint_as_float(v2 & 0xffff0000u) + __uint_as_float(v3 & 0xffff0000u) +
                 __uint_as_float(v4 & 0xffff0000u) + __uint_as_float(v5 & 0xffff0000u) +
                 __uint_as_float(v6 & 0xffff0000u) + __uint_as_float(v7 & 0xffff0000u);
    }
    for (; e + 4 <= end; e += 4) {
        unsigned int v0 = hb[(size_t)es[e] * 64 + lane];
        unsigned int v1 = hb[(size_t)es[e + 1] * 64 + lane];
        unsigned int v2 = hb[(size_t)es[e + 2] * 64 + lane];
        unsigned int v3 = hb[(size_t)es[e + 3] * 64 + lane];
        acc.x += __uint_as_float(v0 << 16) + __uint_as_float(v1 << 16) +
                 __uint_as_float(v2 << 16) + __uint_as_float(v3 << 16);
        acc.y += __uint_as_float(v0 & 0xffff0000u) + __uint_as_float(v1 & 0xffff0000u) +
                 __uint_as_float(v2 & 0xffff0000u) + __uint_as_float(v3 & 0xffff0000u);
    }
    for (; e < end; ++e) {
        unsigned int v = hb[(size_t)es[e] * 64 + lane];
        acc.x += __uint_as_float(v << 16);
        acc.y += __uint_as_float(v & 0xffff0000u);
    }
    ((float2*)t)[(size_t)n * 64 + lane] = acc;
}

__global__ void agg64b_kernel(const unsigned short* __restrict__ xb, const float* __restrict__ xf,
                              const int* __restrict__ row_beg, const int* __restrict__ row_end,
                              const int* __restrict__ es, float* __restrict__ t) {
    int wv = threadIdx.x >> 6, lane = threadIdx.x & 63;
    int n = blockIdx.x * 4 + wv;
    if (n >= NN) return;
    int beg = row_beg[n], end = row_end[n];
    float acc = xf[(size_t)n * 64 + lane];
    int e = beg;
    for (; e + 4 <= end; e += 4) {
        int s0 = es[e], s1 = es[e + 1], s2 = es[e + 2], s3 = es[e + 3];
        acc += bf2f(xb[(size_t)s0 * 64 + lane]) + bf2f(xb[(size_t)s1 * 64 + lane]) +
               bf2f(xb[(size_t)s2 * 64 + lane]) + bf2f(xb[(size_t)s3 * 64 + lane]);
    }
    for (; e < end; ++e) acc += bf2f(xb[(size_t)es[e] * 64 + lane]);
    t[(size_t)n * 64 + lane] = acc;
}

// ---------------- fused2: K=128 GIN layer, phase-resident weights, 3 blocks/CU ------------
// h = relu( relu(t@W1+b1)@W2 + b2 + res ). Wave wv owns cols wv*32..wv*32+31 across all 64
// rows. W1 hi/lo resident (64 VGPR) during GEMM1; SAME registers reloaded with W2 for GEMM2.
// u round-trips through LDS. Epilogue stores direct from acc (16-lane 64B segments).
__global__ __launch_bounds__(256, 3) void fused2(
    const float* __restrict__ tin, const float* __restrict__ xres,
    const short* __restrict__ W1Hi, const short* __restrict__ W1Lo,
    const float* __restrict__ b1, const short* __restrict__ W2Hi,
    const short* __restrict__ W2Lo, const float* __restrict__ b2,
    float* __restrict__ hout, short* __restrict__ hbout) {
    __shared__ short lds[16384];  // hi @ [0..8191], lo @ [8192..16383]
    int tid = threadIdx.x;
    int rowBase = blockIdx.x * 64;
    int lane = tid & 63, wv = tid >> 6;
    int m = lane & 15, g = lane >> 4;

    // issue t-tile loads first (HBM long pole), W1 L2 loads overlap
    float4 sv[8];
#pragma unroll
    for (int j = 0; j < 8; ++j) {
        int i = j * 256 + tid;
        int r = i >> 5, c4 = i & 31;
        int row = rowBase + r;
        sv[j] = f4zero();
        if (row < NN) sv[j] = ((const float4*)(tin + (size_t)row * 128))[c4];
    }
    bf16x8 wh[2][4], wl[2][4];  // phase-resident weight frags (W1 now, W2 later)
#pragma unroll
    for (int ctl = 0; ctl < 2; ++ctl) {
        int col = wv * 32 + ctl * 16 + m;
#pragma unroll
        for (int kc = 0; kc < 4; ++kc) {
            wh[ctl][kc] = *(const bf16x8*)(W1Hi + col * 128 + kc * 32 + g * 8);
            wl[ctl][kc] = *(const bf16x8*)(W1Lo + col * 128 + kc * 32 + g * 8);
        }
    }
    // split + store staged tile (swizzled hi/lo)
#pragma unroll
    for (int j = 0; j < 8; ++j) {
        int i = j * 256 + tid;
        int r = i >> 5, c4 = i & 31;
        float4 v = sv[j];
        unsigned short hx = f2bf(v.x), hy = f2bf(v.y), hz = f2bf(v.z), hw = f2bf(v.w);
        short4 hv = {(short)hx, (short)hy, (short)hz, (short)hw};
        short4 lv = {(short)f2bf(v.x - bf2f(hx)), (short)f2bf(v.y - bf2f(hy)),
                     (short)f2bf(v.z - bf2f(hz)), (short)f2bf(v.w - bf2f(hw))};
        int sidx = (r * 128 + c4 * 4) ^ ((r & 7) << 3);
        *(short4*)(lds + sidx) = hv;
        *(short4*)(lds + 8192 + sidx) = lv;
    }
    __syncthreads();

    // GEMM1: acc1[s][ctl] over 4 row-subtiles; A from LDS, W1 from registers
    f32x4 acc1[4][2];
#pragma unroll
    for (int s = 0; s < 4; ++s) {
        int rloc = s * 16 + m;
        bf16x8 tHi[4], tLo[4];
#pragma unroll
        for (int kc = 0; kc < 4; ++kc) {
            int idx = (rloc * 128 + kc * 32 + g * 8) ^ ((rloc & 7) << 3);
            tHi[kc] = *(const bf16x8*)(lds + idx);
            tLo[kc] = *(const bf16x8*)(lds + 8192 + idx);
        }
#pragma unroll
        for (int ctl = 0; ctl < 2; ++ctl) {
            float bv = b1[wv * 32 + ctl * 16 + m];
            f32x4 a = {bv, bv, bv, bv};
#pragma unroll
            for (int kc = 0; kc < 4; ++kc) {
                a = __builtin_amdgcn_mfma_f32_16x16x32_bf16(tHi[kc], wh[ctl][kc], a, 0, 0, 0);
                a = __builtin_amdgcn_mfma_f32_16x16x32_bf16(tLo[kc], wh[ctl][kc], a, 0, 0, 0);
                a = __builtin_amdgcn_mfma_f32_16x16x32_bf16(tHi[kc], wl[ctl][kc], a, 0, 0, 0);
            }
            acc1[s][ctl] = a;
        }
    }
    __syncthreads();  // all t reads done; LDS free for u

    // u = relu(acc1) -> LDS hi/lo; reload weight registers with W2 (overlaps ds_writes)
#pragma unroll
    for (int s = 0; s < 4; ++s) {
#pragma unroll
        for (int ctl = 0; ctl < 2; ++ctl) {
            int col = wv * 32 + ctl * 16 + m;
#pragma unroll
            for (int i = 0; i < 4; ++i) {
                float u = fmaxf(acc1[s][ctl][i], 0.f);
                unsigned short uh = f2bf(u);
                int ru = s * 16 + g * 4 + i;
                int sidx = (ru * 128 + col) ^ ((ru & 7) << 3);
                lds[sidx] = (short)uh;
                lds[8192 + sidx] = (short)f2bf(u - bf2f(uh));
            }
        }
    }
#pragma unroll
    for (int ctl = 0; ctl < 2; ++ctl) {
        int col = wv * 32 + ctl * 16 + m;
#pragma unroll
        for (int kc = 0; kc < 4; ++kc) {
            wh[ctl][kc] = *(const bf16x8*)(W2Hi + col * 128 + kc * 32 + g * 8);
            wl[ctl][kc] = *(const bf16x8*)(W2Lo + col * 128 + kc * 32 + g * 8);
        }
    }
    __syncthreads();

    // GEMM2 + direct epilogue (res add + relu + h/hb stores)
#pragma unroll
    for (int s = 0; s < 4; ++s) {
        int rloc = s * 16 + m;
        bf16x8 uHi[4], uLo[4];
#pragma unroll
        for (int kc = 0; kc < 4; ++kc) {
            int idx = (rloc * 128 + kc * 32 + g * 8) ^ ((rloc & 7) << 3);
            uHi[kc] = *(const bf16x8*)(lds + idx);
            uLo[kc] = *(const bf16x8*)(lds + 8192 + idx);
        }
#pragma unroll
        for (int ctl = 0; ctl < 2; ++ctl) {
            int col = wv * 32 + ctl * 16 + m;
            float bv = b2[col];
            f32x4 a = {bv, bv, bv, bv};
#pragma unroll
            for (int kc = 0; kc < 4; ++kc) {
                a = __builtin_amdgcn_mfma_f32_16x16x32_bf16(uHi[kc], wh[ctl][kc], a, 0, 0, 0);
                a = __builtin_amdgcn_mfma_f32_16x16x32_bf16(uLo[kc], wh[ctl][kc], a, 0, 0, 0);
                a = __builtin_amdgcn_mfma_f32_16x16x32_bf16(uHi[kc], wl[ctl][kc], a, 0, 0, 0);
            }
#pragma unroll
            for (int i = 0; i < 4; ++i) {
                int row = rowBase + s * 16 + g * 4 + i;
                if (row < NN) {
                    float v = fmaxf(a[i] + xres[(size_t)row * 128 + col], 0.f);
                    hout[(size_t)row * 128 + col] = v;
                    hbout[(size_t)row * 128 + col] = (short)f2bf(v);
                }
            }
        }
    }
}

// ---------------- fused GIN layer 0 (K=64, Wres in-kernel; round-8 structure) ------------
template <int L0>
__global__ __launch_bounds__(256, 4) void fused_layer(
    const float* __restrict__ tin, const float* __restrict__ xres,
    const short* __restrict__ W1Hi, const short* __restrict__ W1Lo,
    const float* __restrict__ b1, const short* __restrict__ W2Hi,
    const short* __restrict__ W2Lo, const float* __restrict__ b2,
    const short* __restrict__ WrHi, const short* __restrict__ WrLo,
    float* __restrict__ hout, short* __restrict__ hbout) {
    constexpr int KIN = L0 ? 64 : 128;
    constexpr int NKC1 = KIN / 32;
    __shared__ short lds[16384];
    int tid = threadIdx.x;
    int rowBase = blockIdx.x * 64;
    int lane = tid & 63, wv = tid >> 6;
    int m = lane & 15, g = lane >> 4;

    for (int i = tid; i < 64 * KIN / 4; i += 256) {
        int r = i / (KIN / 4), c4 = i - r * (KIN / 4);
        int row = rowBase + r;
        float4 v = f4zero();
        if (row < NN) v = ((const float4*)(tin + (size_t)row * KIN))[c4];
        unsigned short hx = f2bf(v.x), hy = f2bf(v.y), hz = f2bf(v.z), hw = f2bf(v.w);
        short4 hv = {(short)hx, (short)hy, (short)hz, (short)hw};
        short4 lv = {(short)f2bf(v.x - bf2f(hx)), (short)f2bf(v.y - bf2f(hy)),
                     (short)f2bf(v.z - bf2f(hz)), (short)f2bf(v.w - bf2f(hw))};
        int sidx = (r * KIN + c4 * 4) ^ ((r & 7) << 3);
        *(short4*)(lds + sidx) = hv;
        *(short4*)(lds + 64 * KIN + sidx) = lv;
    }
    if (L0) {
        for (int i = tid; i < 64 * 64 / 4; i += 256) {
            int r = i >> 4, c4 = i & 15;
            int row = rowBase + r;
            float4 v = f4zero();
            if (row < NN) v = ((const float4*)(xres + (size_t)row * 64))[c4];
            unsigned short hx = f2bf(v.x), hy = f2bf(v.y), hz = f2bf(v.z), hw = f2bf(v.w);
            short4 hv = {(short)hx, (short)hy, (short)hz, (short)hw};
            short4 lv = {(short)f2bf(v.x - bf2f(hx)), (short)f2bf(v.y - bf2f(hy)),
                         (short)f2bf(v.z - bf2f(hz)), (short)f2bf(v.w - bf2f(hw))};
            int sidx = (r * 64 + c4 * 4) ^ ((r & 7) << 3);
            *(short4*)(lds + 8192 + sidx) = hv;
            *(short4*)(lds + 12288 + sidx) = lv;
        }
    }
    __syncthreads();

    int rloc = wv * 16 + m;
    bf16x8 tHi[NKC1], tLo[NKC1];
    bf16x8 xHi[2], xLo[2];
#pragma unroll
    for (int kc = 0; kc < NKC1; ++kc) {
        int idx = (rloc * KIN + kc * 32 + g * 8) ^ ((rloc & 7) << 3);
        tHi[kc] = *(const bf16x8*)(lds + idx);
        tLo[kc] = *(const bf16x8*)(lds + 64 * KIN + idx);
    }
    if (L0) {
#pragma unroll
        for (int kc = 0; kc < 2; ++kc) {
            int idx = (rloc * 64 + kc * 32 + g * 8) ^ ((rloc & 7) << 3);
            xHi[kc] = *(const bf16x8*)(lds + 8192 + idx);
            xLo[kc] = *(const bf16x8*)(lds + 12288 + idx);
        }
    }
    __syncthreads();

    f32x4 racc[8];
#pragma unroll
    for (int ct = 0; ct < 8; ++ct) {
        int col = ct * 16 + m;
        float bv = b1[col];
        f32x4 acc = {bv, bv, bv, bv};
#pragma unroll
        for (int kc = 0; kc < NKC1; ++kc) {
            bf16x8 bhi = *(const bf16x8*)(W1Hi + col * KIN + kc * 32 + g * 8);
            bf16x8 blo = *(const bf16x8*)(W1Lo + col * KIN + kc * 32 + g * 8);
            acc = __builtin_amdgcn_mfma_f32_16x16x32_bf16(tHi[kc], bhi, acc, 0, 0, 0);
            acc = __builtin_amdgcn_mfma_f32_16x16x32_bf16(tLo[kc], bhi, acc, 0, 0, 0);
            acc = __builtin_amdgcn_mfma_f32_16x16x32_bf16(tHi[kc], blo, acc, 0, 0, 0);
        }
        if (L0) {
            f32x4 r = {0.f, 0.f, 0.f, 0.f};
#pragma unroll
            for (int kc = 0; kc < 2; ++kc) {
                bf16x8 bhi = *(const bf16x8*)(WrHi + col * 64 + kc * 32 + g * 8);
                bf16x8 blo = *(const bf16x8*)(WrLo + col * 64 + kc * 32 + g * 8);
                r = __builtin_amdgcn_mfma_f32_16x16x32_bf16(xHi[kc], bhi, r, 0, 0, 0);
                r = __builtin_amdgcn_mfma_f32_16x16x32_bf16(xLo[kc], bhi, r, 0, 0, 0);
                r = __builtin_amdgcn_mfma_f32_16x16x32_bf16(xHi[kc], blo, r, 0, 0, 0);
            }
            racc[ct] = r;
        }
#pragma unroll
        for (int i = 0; i < 4; ++i) {
            float u = fmaxf(acc[i], 0.f);
            unsigned short uh = f2bf(u);
            int ru = wv * 16 + g * 4 + i;
            int sidx = (ru * 128 + col) ^ ((ru & 7) << 3);
            lds[sidx] = (short)uh;
            lds[8192 + sidx] = (short)f2bf(u - bf2f(uh));
        }
    }
    __syncthreads();

    bf16x8 uHi[4], uLo[4];
#pragma unroll
    for (int kc = 0; kc < 4; ++kc) {
        int idx = (rloc * 128 + kc * 32 + g * 8) ^ ((rloc & 7) << 3);
        uHi[kc] = *(const bf16x8*)(lds + idx);
        uLo[kc] = *(const bf16x8*)(lds + 8192 + idx);
    }
    __syncthreads();

    float* fld = (float*)lds;
#pragma unroll
    for (int ct = 0; ct < 8; ++ct) {
        int col = ct * 16 + m;
        float bv = b2[col];
        f32x4 acc = {bv, bv, bv, bv};
#pragma unroll
        for (int kc = 0; kc < 4; ++kc) {
            bf16x8 bhi = *(const bf16x8*)(W2Hi + col * 128 + kc * 32 + g * 8);
            bf16x8 blo = *(const bf16x8*)(W2Lo + col * 128 + kc * 32 + g * 8);
            acc = __builtin_amdgcn_mfma_f32_16x16x32_bf16(uHi[kc], bhi, acc, 0, 0, 0);
            acc = __builtin_amdgcn_mfma_f32_16x16x32_bf16(uLo[kc], bhi, acc, 0, 0, 0);
            acc = __builtin_amdgcn_mfma_f32_16x16x32_bf16(uHi[kc], blo, acc, 0, 0, 0);
        }
#pragma unroll
        for (int i = 0; i < 4; ++i) {
            float v = acc[i];
            if (L0) v = fmaxf(v + racc[ct][i], 0.f);
            int ru = wv * 16 + g * 4 + i;
            int fidx = (ru * 128 + col) ^ ((ru & 7) << 3);
            fld[fidx] = v;
        }
    }
    __syncthreads();

    for (int i = tid; i < 2048; i += 256) {
        int r = i >> 5, c4 = i & 31;
        int row = rowBase + r;
        if (row >= NN) continue;
        int fidx = (r * 128 + c4 * 4) ^ ((r & 7) << 3);
        float4 v = *(const float4*)(fld + fidx);
        if (!L0) {
            float4 rs = ((const float4*)(xres + (size_t)row * 128))[c4];
            v.x = fmaxf(v.x + rs.x, 0.f);
            v.y = fmaxf(v.y + rs.y, 0.f);
            v.z = fmaxf(v.z + rs.z, 0.f);
            v.w = fmaxf(v.w + rs.w, 0.f);
        }
        ((float4*)(hout + (size_t)row * 128))[c4] = v;
        short4 bv4 = {(short)f2bf(v.x), (short)f2bf(v.y), (short)f2bf(v.z), (short)f2bf(v.w)};
        ((short4*)(hbout + (size_t)row * 128))[c4] = bv4;
    }
}

// ---------------- fused mean-pool + FC head ----------------
static __device__ __forceinline__ int lbound(const int* __restrict__ a, int n, int v) {
    int lo = 0, hi = n;
    while (lo < hi) {
        int mid = (lo + hi) >> 1;
        if (a[mid] < v) lo = mid + 1;
        else hi = mid;
    }
    return lo;
}

__global__ void head_kernel(const float* __restrict__ h, const int* __restrict__ batch,
                            const float* __restrict__ fW1, const float* __restrict__ fb1,
                            const float* __restrict__ fW2, const float* __restrict__ fb2,
                            float* __restrict__ out) {
    __shared__ float sp[128];
    __shared__ float su[128];
    __shared__ int sr[2];
    int g = blockIdx.x, t = threadIdx.x;
    if (t == 0) sr[0] = lbound(batch, NN, g);
    if (t == 1) sr[1] = lbound(batch, NN, g + 1);
    __syncthreads();
    int beg = sr[0], end = sr[1];
    float acc = 0.f;
    for (int i = beg; i < end; ++i) acc += h[(size_t)i * 128 + t];
    sp[t] = acc / (float)max(end - beg, 1);
    __syncthreads();
    float a = fb1[t];
#pragma unroll 4
    for (int k = 0; k < 128; ++k) a = fmaf(sp[k], fW1[k * 128 + t], a);
    a = a > 0.f ? a : 0.01f * a;
    su[t] = a * fW2[t];
    __syncthreads();
    for (int s2 = 64; s2 > 0; s2 >>= 1) {
        if (t < s2) su[t] += su[t + s2];
        __syncthreads();
    }
    if (t == 0) out[g] = su[0] + fb2[0];
}

extern "C" void kernel_launch(void* const* d_in, const int* in_sizes, int n_in,
                              void* d_out, int out_size, void* d_ws, size_t ws_size,
                              hipStream_t stream) {
    const float* x = (const float*)d_in[0];
    const int* eidx = (const int*)d_in[1];
    const int* src = eidx;
    const int* dst = eidx + NE;
    const int* batch = (const int*)d_in[2];
    const float* l0_W1 = (const float*)d_in[3];
    const float* l0_b1 = (const float*)d_in[4];
    const float* l0_W2 = (const float*)d_in[5];
    const float* l0_b2 = (const float*)d_in[6];
    const float* l0_Wres = (const float*)d_in[7];
    const float* Ws1 = (const float*)d_in[8];
    const float* bs1 = (const float*)d_in[9];
    const float* Ws2 = (const float*)d_in[10];
    const float* bs2 = (const float*)d_in[11];
    const float* fW1 = (const float*)d_in[12];
    const float* fb1 = (const float*)d_in[13];
    const float* fW2 = (const float*)d_in[14];
    const float* fb2 = (const float*)d_in[15];
    float* out = (float*)d_out;

    size_t used = 0;
    auto alloc = [&](size_t bytes) -> char* {
        char* r = (char*)d_ws + used;
        used = (used + bytes + 255) & ~(size_t)255;
        return r;
    };
    float* A = (float*)alloc((size_t)NN * HID * 4);  // t buffer
    float* B = (float*)alloc((size_t)NN * HID * 4);  // h ping
    float* C = (float*)alloc((size_t)NN * HID * 4);  // h pong
    int* bcur = (int*)alloc((size_t)NBK * 4);
    int* row_beg = (int*)alloc((size_t)NN * 4);
    int* row_end = (int*)alloc((size_t)NN * 4);
    int* esrc = (int*)alloc((size_t)NBK * BCAP * 4);
    // bedge (4.0MB) aliases xb (6.4MB): bedge dead after build_csr
    char* shared_region = alloc((size_t)NN * IND * 2 > (size_t)NBK * BCAP * 4
                                    ? (size_t)NN * IND * 2
                                    : (size_t)NBK * BCAP * 4);
    unsigned int* bedge = (unsigned int*)shared_region;
    short* xb = (short*)shared_region;
    short* wresHi = (short*)alloc(128 * 64 * 2);
    short* wresLo = (short*)alloc(128 * 64 * 2);
    short* w1Hi = (short*)alloc(128 * 64 * 2);
    short* w1Lo = (short*)alloc(128 * 64 * 2);
    short* w2Hi = (short*)alloc(128 * 128 * 2);
    short* w2Lo = (short*)alloc(128 * 128 * 2);
    short* ws1Hi = (short*)alloc(3 * 128 * 128 * 2);
    short* ws1Lo = (short*)alloc(3 * 128 * 128 * 2);
    short* ws2Hi = (short*)alloc(3 * 128 * 128 * 2);
    short* ws2Lo = (short*)alloc(3 * 128 * 128 * 2);
    short* hb = (short*)alloc((size_t)NN * HID * 2);

    hipMemsetAsync(bcur, 0, (size_t)NBK * 4, stream);

    const int GB = (NN + 63) / 64;   // 782
    const int AGGB = (NN + 3) / 4;   // 12500

    convert_all<<<512, 256, 0, stream>>>(l0_Wres, l0_W1, l0_W2, Ws1, Ws2, wresHi, wresLo, w1Hi,
                                         w1Lo, w2Hi, w2Lo, ws1Hi, ws1Lo, ws2Hi, ws2Lo);

    bin_kernel<<<(NE + 4095) / 4096, 256, 0, stream>>>(src, dst, bcur, bedge);
    build_csr_kernel<<<NBK, 256, 0, stream>>>(bedge, bcur, row_beg, row_end, esrc);

    to_bf16_kernel<<<(NN * IND + 255) / 256, 256, 0, stream>>>(x, xb, NN * IND);

    // layer 0: t0 = x + agg(x) -> A; h0 = fused(A, x) -> B (+ hb)
    agg64b_kernel<<<AGGB, 256, 0, stream>>>((const unsigned short*)xb, x, row_beg, row_end, esrc,
                                            A);
    fused_layer<1><<<GB, 256, 0, stream>>>(A, x, w1Hi, w1Lo, l0_b1, w2Hi, w2Lo, l0_b2, wresHi,
                                           wresLo, B, hb);

    // layers 1..3: t = h + agg(hb) -> A; h' = fused2(A, h) -> ping-pong (+ hb)
    float* hcur = B;
    float* hnxt = C;
    for (int l = 0; l < 3; ++l) {
        agg128b_kernel<<<AGGB, 256, 0, stream>>>((const unsigned int*)hb, hcur, row_beg, row_end,
                                                 esrc, A);
        fused2<<<GB, 256, 0, stream>>>(A, hcur, ws1Hi + (size_t)l * 16384,
                                       ws1Lo + (size_t)l * 16384, bs1 + (size_t)l * HID,
                                       ws2Hi + (size_t)l * 16384, ws2Lo + (size_t)l * 16384,
                                       bs2 + (size_t)l * HID, hnxt, hb);
        float* t2 = hcur;
        hcur = hnxt;
        hnxt = t2;
    }

    head_kernel<<<NG, 128, 0, stream>>>(hcur, batch, fW1, fb1, fW2, fb2, out);
}

// Round 10
// 435.214 us; speedup vs baseline: 1.9069x; 1.0784x over previous
//
#include <hip/hip_runtime.h>

#define NN 50000
#define NE 800000
#define IND 64
#define HID 128
#define NG 1024

#define NBK 391   // buckets of 128 dst nodes
#define BCAP 2560 // padded capacity per bucket (avg 2046, +11 sigma)

typedef short bf16x8 __attribute__((ext_vector_type(8)));
typedef float f32x4 __attribute__((ext_vector_type(4)));

static __device__ __forceinline__ unsigned short f2bf(float f) {
    unsigned int u = __float_as_uint(f);
    return (unsigned short)((u + 0x7FFFu + ((u >> 16) & 1u)) >> 16);
}
static __device__ __forceinline__ float bf2f(unsigned short h) {
    return __uint_as_float(((unsigned int)h) << 16);
}
static __device__ __forceinline__ float4 f4zero() { return make_float4(0.f, 0.f, 0.f, 0.f); }

// ---------------- bucketed CSR build ----------------
__global__ void bin_kernel(const int* __restrict__ src, const int* __restrict__ dst,
                           int* __restrict__ bcur, unsigned int* __restrict__ bedge) {
    __shared__ int hist[NBK];
    __shared__ int base[NBK];
    int tid = threadIdx.x;
    for (int i = tid; i < NBK; i += 256) hist[i] = 0;
    __syncthreads();
    int e0 = blockIdx.x * 4096;
    unsigned int pk[16];
    int bk[16], lo[16];
#pragma unroll
    for (int j = 0; j < 16; ++j) {
        int e = e0 + j * 256 + tid;
        bk[j] = -1;
        if (e < NE) {
            int s = src[e], d = dst[e];
            pk[j] = (unsigned int)s | ((unsigned int)d << 16);
            bk[j] = d >> 7;
            lo[j] = atomicAdd(&hist[bk[j]], 1);
        }
    }
    __syncthreads();
    for (int i = tid; i < NBK; i += 256)
        base[i] = hist[i] ? atomicAdd(&bcur[i], hist[i]) : 0;
    __syncthreads();
#pragma unroll
    for (int j = 0; j < 16; ++j) {
        if (bk[j] >= 0) {
            int idx = base[bk[j]] + lo[j];
            if (idx < BCAP) bedge[(size_t)bk[j] * BCAP + idx] = pk[j];
        }
    }
}

__global__ void build_csr_kernel(const unsigned int* __restrict__ bedge,
                                 const int* __restrict__ bcur, int* __restrict__ row_beg,
                                 int* __restrict__ row_end, int* __restrict__ esrc) {
    __shared__ unsigned int se[BCAP];
    __shared__ int h[128], sc[128], cur[128];
    int b = blockIdx.x, tid = threadIdx.x;
    int cnt = min(bcur[b], BCAP);
    for (int i = tid; i < cnt; i += 256) se[i] = bedge[(size_t)b * BCAP + i];
    if (tid < 128) h[tid] = 0;
    __syncthreads();
    for (int i = tid; i < cnt; i += 256) atomicAdd(&h[(se[i] >> 16) & 127], 1);
    __syncthreads();
    if (tid < 128) sc[tid] = h[tid];
    __syncthreads();
    for (int off = 1; off < 128; off <<= 1) {
        int add = 0;
        if (tid < 128 && tid >= off) add = sc[tid - off];
        __syncthreads();
        if (tid < 128) sc[tid] += add;
        __syncthreads();
    }
    if (tid < 128) {
        int ex = sc[tid] - h[tid];
        int n = (b << 7) + tid;
        if (n < NN) {
            row_beg[n] = b * BCAP + ex;
            row_end[n] = b * BCAP + sc[tid];
        }
        cur[tid] = ex;
    }
    __syncthreads();
    for (int i = tid; i < cnt; i += 256) {
        unsigned int v = se[i];
        int dl = (v >> 16) & 127;
        int pos = atomicAdd(&cur[dl], 1);
        esrc[(size_t)b * BCAP + pos] = (int)(v & 0xffffu);
    }
}

// ---------------- weight convert: W[K][128] fp32 -> Wt hi/lo [128][K] bf16 ----------------
__global__ void convert_all(const float* __restrict__ Wres, const float* __restrict__ W1,
                            const float* __restrict__ W2, const float* __restrict__ Ws1,
                            const float* __restrict__ Ws2, short* __restrict__ wresHi,
                            short* __restrict__ wresLo, short* __restrict__ w1Hi,
                            short* __restrict__ w1Lo, short* __restrict__ w2Hi,
                            short* __restrict__ w2Lo, short* __restrict__ ws1Hi,
                            short* __restrict__ ws1Lo, short* __restrict__ ws2Hi,
                            short* __restrict__ ws2Lo) {
    int t = blockIdx.x * 256 + threadIdx.x;
    const float* W;
    short *hi, *lo;
    int K, idx;
    if (t < 8192) { W = Wres; hi = wresHi; lo = wresLo; K = 64; idx = t; }
    else if (t < 16384) { W = W1; hi = w1Hi; lo = w1Lo; K = 64; idx = t - 8192; }
    else if (t < 32768) { W = W2; hi = w2Hi; lo = w2Lo; K = 128; idx = t - 16384; }
    else if (t < 81920) { W = Ws1; hi = ws1Hi; lo = ws1Lo; K = 128; idx = t - 32768; }
    else { W = Ws2; hi = ws2Hi; lo = ws2Lo; K = 128; idx = t - 81920; }
    int m = idx / (K * 128);
    int r = idx - m * K * 128;
    int n = r / K, k = r - n * K;
    float w = W[(size_t)m * K * 128 + k * 128 + n];
    unsigned short hh = f2bf(w);
    hi[idx] = (short)hh;
    lo[idx] = (short)f2bf(w - bf2f(hh));
}

__global__ void to_bf16_kernel(const float* __restrict__ s, short* __restrict__ d, int total) {
    int i = blockIdx.x * 256 + threadIdx.x;
    if (i < total) d[i] = (short)f2bf(s[i]);
}

// ---------------- bf16 gather aggregation, exact fp32 self term ----------------
__global__ void agg128b_kernel(const unsigned int* __restrict__ hb, const float* __restrict__ hf,
                               const int* __restrict__ row_beg, const int* __restrict__ row_end,
                               const int* __restrict__ es, float* __restrict__ t) {
    int wv = threadIdx.x >> 6, lane = threadIdx.x & 63;
    int n = blockIdx.x * 4 + wv;
    if (n >= NN) return;
    int beg = row_beg[n], end = row_end[n];
    float2 acc = ((const float2*)hf)[(size_t)n * 64 + lane];
    int e = beg;
    for (; e + 8 <= end; e += 8) {
        unsigned int v0 = hb[(size_t)es[e] * 64 + lane];
        unsigned int v1 = hb[(size_t)es[e + 1] * 64 + lane];
        unsigned int v2 = hb[(size_t)es[e + 2] * 64 + lane];
        unsigned int v3 = hb[(size_t)es[e + 3] * 64 + lane];
        unsigned int v4 = hb[(size_t)es[e + 4] * 64 + lane];
        unsigned int v5 = hb[(size_t)es[e + 5] * 64 + lane];
        unsigned int v6 = hb[(size_t)es[e + 6] * 64 + lane];
        unsigned int v7 = hb[(size_t)es[e + 7] * 64 + lane];
        acc.x += __uint_as_float(v0 << 16) + __uint_as_float(v1 << 16) +
                 __uint_as_float(v2 << 16) + __uint_as_float(v3 << 16) +
                 __uint_as_float(v4 << 16) + __uint_as_float(v5 << 16) +
                 __uint_as_float(v6 << 16) + __uint_as_float(v7 << 16);
        acc.y += __uint_as_float(v0 & 0xffff0000u) + __uint_as_float(v1 & 0xffff0000u) +
                 __uint_as_float(v2 & 0xffff0000u) + __uint_as_float(v3 & 0xffff0000u) +
                 __uint_as_float(v4 & 0xffff0000u) + __uint_as_float(v5 & 0xffff0000u) +
                 __uint_as_float(v6 & 0xffff0000u) + __uint_as_float(v7 & 0xffff0000u);
    }
    for (; e + 4 <= end; e += 4) {
        unsigned int v0 = hb[(size_t)es[e] * 64 + lane];
        unsigned int v1 = hb[(size_t)es[e + 1] * 64 + lane];
        unsigned int v2 = hb[(size_t)es[e + 2] * 64 + lane];
        unsigned int v3 = hb[(size_t)es[e + 3] * 64 + lane];
        acc.x += __uint_as_float(v0 << 16) + __uint_as_float(v1 << 16) +
                 __uint_as_float(v2 << 16) + __uint_as_float(v3 << 16);
        acc.y += __uint_as_float(v0 & 0xffff0000u) + __uint_as_float(v1 & 0xffff0000u) +
                 __uint_as_float(v2 & 0xffff0000u) + __uint_as_float(v3 & 0xffff0000u);
    }
    for (; e < end; ++e) {
        unsigned int v = hb[(size_t)es[e] * 64 + lane];
        acc.x += __uint_as_float(v << 16);
        acc.y += __uint_as_float(v & 0xffff0000u);
    }
    ((float2*)t)[(size_t)n * 64 + lane] = acc;
}

__global__ void agg64b_kernel(const unsigned short* __restrict__ xb, const float* __restrict__ xf,
                              const int* __restrict__ row_beg, const int* __restrict__ row_end,
                              const int* __restrict__ es, float* __restrict__ t) {
    int wv = threadIdx.x >> 6, lane = threadIdx.x & 63;
    int n = blockIdx.x * 4 + wv;
    if (n >= NN) return;
    int beg = row_beg[n], end = row_end[n];
    float acc = xf[(size_t)n * 64 + lane];
    int e = beg;
    for (; e + 4 <= end; e += 4) {
        int s0 = es[e], s1 = es[e + 1], s2 = es[e + 2], s3 = es[e + 3];
        acc += bf2f(xb[(size_t)s0 * 64 + lane]) + bf2f(xb[(size_t)s1 * 64 + lane]) +
               bf2f(xb[(size_t)s2 * 64 + lane]) + bf2f(xb[(size_t)s3 * 64 + lane]);
    }
    for (; e < end; ++e) acc += bf2f(xb[(size_t)es[e] * 64 + lane]);
    t[(size_t)n * 64 + lane] = acc;
}

// ---------------- fused2: K=128 GIN layer, phase-resident weights, 3 blocks/CU ------------
__global__ __launch_bounds__(256, 3) void fused2(
    const float* __restrict__ tin, const float* __restrict__ xres,
    const short* __restrict__ W1Hi, const short* __restrict__ W1Lo,
    const float* __restrict__ b1, const short* __restrict__ W2Hi,
    const short* __restrict__ W2Lo, const float* __restrict__ b2,
    float* __restrict__ hout, short* __restrict__ hbout) {
    __shared__ short lds[16384];  // hi @ [0..8191], lo @ [8192..16383]
    int tid = threadIdx.x;
    int rowBase = blockIdx.x * 64;
    int lane = tid & 63, wv = tid >> 6;
    int m = lane & 15, g = lane >> 4;

    float4 sv[8];
#pragma unroll
    for (int j = 0; j < 8; ++j) {
        int i = j * 256 + tid;
        int r = i >> 5, c4 = i & 31;
        int row = rowBase + r;
        sv[j] = f4zero();
        if (row < NN) sv[j] = ((const float4*)(tin + (size_t)row * 128))[c4];
    }
    bf16x8 wh[2][4], wl[2][4];
#pragma unroll
    for (int ctl = 0; ctl < 2; ++ctl) {
        int col = wv * 32 + ctl * 16 + m;
#pragma unroll
        for (int kc = 0; kc < 4; ++kc) {
            wh[ctl][kc] = *(const bf16x8*)(W1Hi + col * 128 + kc * 32 + g * 8);
            wl[ctl][kc] = *(const bf16x8*)(W1Lo + col * 128 + kc * 32 + g * 8);
        }
    }
#pragma unroll
    for (int j = 0; j < 8; ++j) {
        int i = j * 256 + tid;
        int r = i >> 5, c4 = i & 31;
        float4 v = sv[j];
        unsigned short hx = f2bf(v.x), hy = f2bf(v.y), hz = f2bf(v.z), hw = f2bf(v.w);
        short4 hv = {(short)hx, (short)hy, (short)hz, (short)hw};
        short4 lv = {(short)f2bf(v.x - bf2f(hx)), (short)f2bf(v.y - bf2f(hy)),
                     (short)f2bf(v.z - bf2f(hz)), (short)f2bf(v.w - bf2f(hw))};
        int sidx = (r * 128 + c4 * 4) ^ ((r & 7) << 3);
        *(short4*)(lds + sidx) = hv;
        *(short4*)(lds + 8192 + sidx) = lv;
    }
    __syncthreads();

    f32x4 acc1[4][2];
#pragma unroll
    for (int s = 0; s < 4; ++s) {
        int rloc = s * 16 + m;
        bf16x8 tHi[4], tLo[4];
#pragma unroll
        for (int kc = 0; kc < 4; ++kc) {
            int idx = (rloc * 128 + kc * 32 + g * 8) ^ ((rloc & 7) << 3);
            tHi[kc] = *(const bf16x8*)(lds + idx);
            tLo[kc] = *(const bf16x8*)(lds + 8192 + idx);
        }
#pragma unroll
        for (int ctl = 0; ctl < 2; ++ctl) {
            float bv = b1[wv * 32 + ctl * 16 + m];
            f32x4 a = {bv, bv, bv, bv};
#pragma unroll
            for (int kc = 0; kc < 4; ++kc) {
                a = __builtin_amdgcn_mfma_f32_16x16x32_bf16(tHi[kc], wh[ctl][kc], a, 0, 0, 0);
                a = __builtin_amdgcn_mfma_f32_16x16x32_bf16(tLo[kc], wh[ctl][kc], a, 0, 0, 0);
                a = __builtin_amdgcn_mfma_f32_16x16x32_bf16(tHi[kc], wl[ctl][kc], a, 0, 0, 0);
            }
            acc1[s][ctl] = a;
        }
    }
    __syncthreads();

#pragma unroll
    for (int s = 0; s < 4; ++s) {
#pragma unroll
        for (int ctl = 0; ctl < 2; ++ctl) {
            int col = wv * 32 + ctl * 16 + m;
#pragma unroll
            for (int i = 0; i < 4; ++i) {
                float u = fmaxf(acc1[s][ctl][i], 0.f);
                unsigned short uh = f2bf(u);
                int ru = s * 16 + g * 4 + i;
                int sidx = (ru * 128 + col) ^ ((ru & 7) << 3);
                lds[sidx] = (short)uh;
                lds[8192 + sidx] = (short)f2bf(u - bf2f(uh));
            }
        }
    }
#pragma unroll
    for (int ctl = 0; ctl < 2; ++ctl) {
        int col = wv * 32 + ctl * 16 + m;
#pragma unroll
        for (int kc = 0; kc < 4; ++kc) {
            wh[ctl][kc] = *(const bf16x8*)(W2Hi + col * 128 + kc * 32 + g * 8);
            wl[ctl][kc] = *(const bf16x8*)(W2Lo + col * 128 + kc * 32 + g * 8);
        }
    }
    __syncthreads();

#pragma unroll
    for (int s = 0; s < 4; ++s) {
        int rloc = s * 16 + m;
        bf16x8 uHi[4], uLo[4];
#pragma unroll
        for (int kc = 0; kc < 4; ++kc) {
            int idx = (rloc * 128 + kc * 32 + g * 8) ^ ((rloc & 7) << 3);
            uHi[kc] = *(const bf16x8*)(lds + idx);
            uLo[kc] = *(const bf16x8*)(lds + 8192 + idx);
        }
#pragma unroll
        for (int ctl = 0; ctl < 2; ++ctl) {
            int col = wv * 32 + ctl * 16 + m;
            float bv = b2[col];
            f32x4 a = {bv, bv, bv, bv};
#pragma unroll
            for (int kc = 0; kc < 4; ++kc) {
                a = __builtin_amdgcn_mfma_f32_16x16x32_bf16(uHi[kc], wh[ctl][kc], a, 0, 0, 0);
                a = __builtin_amdgcn_mfma_f32_16x16x32_bf16(uLo[kc], wh[ctl][kc], a, 0, 0, 0);
                a = __builtin_amdgcn_mfma_f32_16x16x32_bf16(uHi[kc], wl[ctl][kc], a, 0, 0, 0);
            }
#pragma unroll
            for (int i = 0; i < 4; ++i) {
                int row = rowBase + s * 16 + g * 4 + i;
                if (row < NN) {
                    float v = fmaxf(a[i] + xres[(size_t)row * 128 + col], 0.f);
                    hout[(size_t)row * 128 + col] = v;
                    hbout[(size_t)row * 128 + col] = (short)f2bf(v);
                }
            }
        }
    }
}

// ---------------- fused0: layer 0 (K=64 + in-register Wres residual), fused2 structure ----
// h = relu( relu(t@W1+b1)@W2 + b2 + x@Wres ). Phase 1 register file holds W1 (frags [0..1])
// AND Wres (frags [2..3]); phase 2 reloads all 4 slots with W2 (K=128). racc kept in regs.
__global__ __launch_bounds__(256, 3) void fused0(
    const float* __restrict__ tin, const float* __restrict__ x,
    const short* __restrict__ W1Hi, const short* __restrict__ W1Lo,
    const float* __restrict__ b1, const short* __restrict__ W2Hi,
    const short* __restrict__ W2Lo, const float* __restrict__ b2,
    const short* __restrict__ WrHi, const short* __restrict__ WrLo,
    float* __restrict__ hout, short* __restrict__ hbout) {
    __shared__ short lds[16384];  // ph1: tHi@0 tLo@4096 xHi@8192 xLo@12288; ph2: uHi@0 uLo@8192
    int tid = threadIdx.x;
    int rowBase = blockIdx.x * 64;
    int lane = tid & 63, wv = tid >> 6;
    int m = lane & 15, g = lane >> 4;

    // issue staged loads (t and x tiles, [64][64] each)
    float4 sv[4], sx[4];
#pragma unroll
    for (int j = 0; j < 4; ++j) {
        int i = j * 256 + tid;
        int r = i >> 4, c4 = i & 15;
        int row = rowBase + r;
        sv[j] = f4zero();
        sx[j] = f4zero();
        if (row < NN) {
            sv[j] = ((const float4*)(tin + (size_t)row * 64))[c4];
            sx[j] = ((const float4*)(x + (size_t)row * 64))[c4];
        }
    }
    // phase-1 weights: W1 in slots [0..1], Wres in slots [2..3]
    bf16x8 wh[2][4], wl[2][4];
#pragma unroll
    for (int ctl = 0; ctl < 2; ++ctl) {
        int col = wv * 32 + ctl * 16 + m;
#pragma unroll
        for (int kc = 0; kc < 2; ++kc) {
            wh[ctl][kc] = *(const bf16x8*)(W1Hi + col * 64 + kc * 32 + g * 8);
            wl[ctl][kc] = *(const bf16x8*)(W1Lo + col * 64 + kc * 32 + g * 8);
            wh[ctl][2 + kc] = *(const bf16x8*)(WrHi + col * 64 + kc * 32 + g * 8);
            wl[ctl][2 + kc] = *(const bf16x8*)(WrLo + col * 64 + kc * 32 + g * 8);
        }
    }
    // split + store staged tiles (swizzled hi/lo)
#pragma unroll
    for (int j = 0; j < 4; ++j) {
        int i = j * 256 + tid;
        int r = i >> 4, c4 = i & 15;
        int sidx = (r * 64 + c4 * 4) ^ ((r & 7) << 3);
        float4 v = sv[j];
        unsigned short hx = f2bf(v.x), hy = f2bf(v.y), hz = f2bf(v.z), hw = f2bf(v.w);
        short4 hv = {(short)hx, (short)hy, (short)hz, (short)hw};
        short4 lv = {(short)f2bf(v.x - bf2f(hx)), (short)f2bf(v.y - bf2f(hy)),
                     (short)f2bf(v.z - bf2f(hz)), (short)f2bf(v.w - bf2f(hw))};
        *(short4*)(lds + sidx) = hv;
        *(short4*)(lds + 4096 + sidx) = lv;
        v = sx[j];
        hx = f2bf(v.x), hy = f2bf(v.y), hz = f2bf(v.z), hw = f2bf(v.w);
        short4 hv2 = {(short)hx, (short)hy, (short)hz, (short)hw};
        short4 lv2 = {(short)f2bf(v.x - bf2f(hx)), (short)f2bf(v.y - bf2f(hy)),
                      (short)f2bf(v.z - bf2f(hz)), (short)f2bf(v.w - bf2f(hw))};
        *(short4*)(lds + 8192 + sidx) = hv2;
        *(short4*)(lds + 12288 + sidx) = lv2;
    }
    __syncthreads();

    // GEMM1 (t@W1, K=64) + residual (x@Wres, K=64)
    f32x4 acc1[4][2], racc[4][2];
#pragma unroll
    for (int s = 0; s < 4; ++s) {
        int rloc = s * 16 + m;
        bf16x8 tH[2], tL[2], xH[2], xL[2];
#pragma unroll
        for (int kc = 0; kc < 2; ++kc) {
            int idx = (rloc * 64 + kc * 32 + g * 8) ^ ((rloc & 7) << 3);
            tH[kc] = *(const bf16x8*)(lds + idx);
            tL[kc] = *(const bf16x8*)(lds + 4096 + idx);
            xH[kc] = *(const bf16x8*)(lds + 8192 + idx);
            xL[kc] = *(const bf16x8*)(lds + 12288 + idx);
        }
#pragma unroll
        for (int ctl = 0; ctl < 2; ++ctl) {
            float bv = b1[wv * 32 + ctl * 16 + m];
            f32x4 a = {bv, bv, bv, bv};
            f32x4 r4 = {0.f, 0.f, 0.f, 0.f};
#pragma unroll
            for (int kc = 0; kc < 2; ++kc) {
                a = __builtin_amdgcn_mfma_f32_16x16x32_bf16(tH[kc], wh[ctl][kc], a, 0, 0, 0);
                a = __builtin_amdgcn_mfma_f32_16x16x32_bf16(tL[kc], wh[ctl][kc], a, 0, 0, 0);
                a = __builtin_amdgcn_mfma_f32_16x16x32_bf16(tH[kc], wl[ctl][kc], a, 0, 0, 0);
                r4 = __builtin_amdgcn_mfma_f32_16x16x32_bf16(xH[kc], wh[ctl][2 + kc], r4, 0, 0, 0);
                r4 = __builtin_amdgcn_mfma_f32_16x16x32_bf16(xL[kc], wh[ctl][2 + kc], r4, 0, 0, 0);
                r4 = __builtin_amdgcn_mfma_f32_16x16x32_bf16(xH[kc], wl[ctl][2 + kc], r4, 0, 0, 0);
            }
            acc1[s][ctl] = a;
            racc[s][ctl] = r4;
        }
    }
    __syncthreads();  // t/x reads done; LDS free for u

    // u = relu(acc1) -> LDS [64][128] hi/lo; reload weight regs with W2
#pragma unroll
    for (int s = 0; s < 4; ++s) {
#pragma unroll
        for (int ctl = 0; ctl < 2; ++ctl) {
            int col = wv * 32 + ctl * 16 + m;
#pragma unroll
            for (int i = 0; i < 4; ++i) {
                float u = fmaxf(acc1[s][ctl][i], 0.f);
                unsigned short uh = f2bf(u);
                int ru = s * 16 + g * 4 + i;
                int sidx = (ru * 128 + col) ^ ((ru & 7) << 3);
                lds[sidx] = (short)uh;
                lds[8192 + sidx] = (short)f2bf(u - bf2f(uh));
            }
        }
    }
#pragma unroll
    for (int ctl = 0; ctl < 2; ++ctl) {
        int col = wv * 32 + ctl * 16 + m;
#pragma unroll
        for (int kc = 0; kc < 4; ++kc) {
            wh[ctl][kc] = *(const bf16x8*)(W2Hi + col * 128 + kc * 32 + g * 8);
            wl[ctl][kc] = *(const bf16x8*)(W2Lo + col * 128 + kc * 32 + g * 8);
        }
    }
    __syncthreads();

    // GEMM2 + epilogue: h = relu(u@W2 + b2 + racc)
#pragma unroll
    for (int s = 0; s < 4; ++s) {
        int rloc = s * 16 + m;
        bf16x8 uHi[4], uLo[4];
#pragma unroll
        for (int kc = 0; kc < 4; ++kc) {
            int idx = (rloc * 128 + kc * 32 + g * 8) ^ ((rloc & 7) << 3);
            uHi[kc] = *(const bf16x8*)(lds + idx);
            uLo[kc] = *(const bf16x8*)(lds + 8192 + idx);
        }
#pragma unroll
        for (int ctl = 0; ctl < 2; ++ctl) {
            int col = wv * 32 + ctl * 16 + m;
            float bv = b2[col];
            f32x4 a = {bv, bv, bv, bv};
#pragma unroll
            for (int kc = 0; kc < 4; ++kc) {
                a = __builtin_amdgcn_mfma_f32_16x16x32_bf16(uHi[kc], wh[ctl][kc], a, 0, 0, 0);
                a = __builtin_amdgcn_mfma_f32_16x16x32_bf16(uLo[kc], wh[ctl][kc], a, 0, 0, 0);
                a = __builtin_amdgcn_mfma_f32_16x16x32_bf16(uHi[kc], wl[ctl][kc], a, 0, 0, 0);
            }
#pragma unroll
            for (int i = 0; i < 4; ++i) {
                int row = rowBase + s * 16 + g * 4 + i;
                if (row < NN) {
                    float v = fmaxf(a[i] + racc[s][ctl][i], 0.f);
                    hout[(size_t)row * 128 + col] = v;
                    hbout[(size_t)row * 128 + col] = (short)f2bf(v);
                }
            }
        }
    }
}

// ---------------- fused mean-pool + FC head ----------------
static __device__ __forceinline__ int lbound(const int* __restrict__ a, int n, int v) {
    int lo = 0, hi = n;
    while (lo < hi) {
        int mid = (lo + hi) >> 1;
        if (a[mid] < v) lo = mid + 1;
        else hi = mid;
    }
    return lo;
}

__global__ void head_kernel(const float* __restrict__ h, const int* __restrict__ batch,
                            const float* __restrict__ fW1, const float* __restrict__ fb1,
                            const float* __restrict__ fW2, const float* __restrict__ fb2,
                            float* __restrict__ out) {
    __shared__ float sp[128];
    __shared__ float su[128];
    __shared__ int sr[2];
    int g = blockIdx.x, t = threadIdx.x;
    if (t == 0) sr[0] = lbound(batch, NN, g);
    if (t == 1) sr[1] = lbound(batch, NN, g + 1);
    __syncthreads();
    int beg = sr[0], end = sr[1];
    float acc = 0.f;
    for (int i = beg; i < end; ++i) acc += h[(size_t)i * 128 + t];
    sp[t] = acc / (float)max(end - beg, 1);
    __syncthreads();
    float a = fb1[t];
#pragma unroll 4
    for (int k = 0; k < 128; ++k) a = fmaf(sp[k], fW1[k * 128 + t], a);
    a = a > 0.f ? a : 0.01f * a;
    su[t] = a * fW2[t];
    __syncthreads();
    for (int s2 = 64; s2 > 0; s2 >>= 1) {
        if (t < s2) su[t] += su[t + s2];
        __syncthreads();
    }
    if (t == 0) out[g] = su[0] + fb2[0];
}

extern "C" void kernel_launch(void* const* d_in, const int* in_sizes, int n_in,
                              void* d_out, int out_size, void* d_ws, size_t ws_size,
                              hipStream_t stream) {
    const float* x = (const float*)d_in[0];
    const int* eidx = (const int*)d_in[1];
    const int* src = eidx;
    const int* dst = eidx + NE;
    const int* batch = (const int*)d_in[2];
    const float* l0_W1 = (const float*)d_in[3];
    const float* l0_b1 = (const float*)d_in[4];
    const float* l0_W2 = (const float*)d_in[5];
    const float* l0_b2 = (const float*)d_in[6];
    const float* l0_Wres = (const float*)d_in[7];
    const float* Ws1 = (const float*)d_in[8];
    const float* bs1 = (const float*)d_in[9];
    const float* Ws2 = (const float*)d_in[10];
    const float* bs2 = (const float*)d_in[11];
    const float* fW1 = (const float*)d_in[12];
    const float* fb1 = (const float*)d_in[13];
    const float* fW2 = (const float*)d_in[14];
    const float* fb2 = (const float*)d_in[15];
    float* out = (float*)d_out;

    size_t used = 0;
    auto alloc = [&](size_t bytes) -> char* {
        char* r = (char*)d_ws + used;
        used = (used + bytes + 255) & ~(size_t)255;
        return r;
    };
    float* A = (float*)alloc((size_t)NN * HID * 4);  // t buffer
    float* B = (float*)alloc((size_t)NN * HID * 4);  // h ping
    float* C = (float*)alloc((size_t)NN * HID * 4);  // h pong
    int* bcur = (int*)alloc((size_t)NBK * 4);
    int* row_beg = (int*)alloc((size_t)NN * 4);
    int* row_end = (int*)alloc((size_t)NN * 4);
    int* esrc = (int*)alloc((size_t)NBK * BCAP * 4);
    // bedge (4.0MB) aliases xb (6.4MB): bedge dead after build_csr
    char* shared_region = alloc((size_t)NN * IND * 2 > (size_t)NBK * BCAP * 4
                                    ? (size_t)NN * IND * 2
                                    : (size_t)NBK * BCAP * 4);
    unsigned int* bedge = (unsigned int*)shared_region;
    short* xb = (short*)shared_region;
    short* wresHi = (short*)alloc(128 * 64 * 2);
    short* wresLo = (short*)alloc(128 * 64 * 2);
    short* w1Hi = (short*)alloc(128 * 64 * 2);
    short* w1Lo = (short*)alloc(128 * 64 * 2);
    short* w2Hi = (short*)alloc(128 * 128 * 2);
    short* w2Lo = (short*)alloc(128 * 128 * 2);
    short* ws1Hi = (short*)alloc(3 * 128 * 128 * 2);
    short* ws1Lo = (short*)alloc(3 * 128 * 128 * 2);
    short* ws2Hi = (short*)alloc(3 * 128 * 128 * 2);
    short* ws2Lo = (short*)alloc(3 * 128 * 128 * 2);
    short* hb = (short*)alloc((size_t)NN * HID * 2);

    hipMemsetAsync(bcur, 0, (size_t)NBK * 4, stream);

    const int GB = (NN + 63) / 64;   // 782
    const int AGGB = (NN + 3) / 4;   // 12500

    convert_all<<<512, 256, 0, stream>>>(l0_Wres, l0_W1, l0_W2, Ws1, Ws2, wresHi, wresLo, w1Hi,
                                         w1Lo, w2Hi, w2Lo, ws1Hi, ws1Lo, ws2Hi, ws2Lo);

    bin_kernel<<<(NE + 4095) / 4096, 256, 0, stream>>>(src, dst, bcur, bedge);
    build_csr_kernel<<<NBK, 256, 0, stream>>>(bedge, bcur, row_beg, row_end, esrc);

    to_bf16_kernel<<<(NN * IND + 255) / 256, 256, 0, stream>>>(x, xb, NN * IND);

    // layer 0: t0 = x + agg(x) -> A; h0 = fused0(A, x) -> B (+ hb)
    agg64b_kernel<<<AGGB, 256, 0, stream>>>((const unsigned short*)xb, x, row_beg, row_end, esrc,
                                            A);
    fused0<<<GB, 256, 0, stream>>>(A, x, w1Hi, w1Lo, l0_b1, w2Hi, w2Lo, l0_b2, wresHi, wresLo, B,
                                   hb);

    // layers 1..3: t = h + agg(hb) -> A; h' = fused2(A, h) -> ping-pong (+ hb)
    float* hcur = B;
    float* hnxt = C;
    for (int l = 0; l < 3; ++l) {
        agg128b_kernel<<<AGGB, 256, 0, stream>>>((const unsigned int*)hb, hcur, row_beg, row_end,
                                                 esrc, A);
        fused2<<<GB, 256, 0, stream>>>(A, hcur, ws1Hi + (size_t)l * 16384,
                                       ws1Lo + (size_t)l * 16384, bs1 + (size_t)l * HID,
                                       ws2Hi + (size_t)l * 16384, ws2Lo + (size_t)l * 16384,
                                       bs2 + (size_t)l * HID, hnxt, hb);
        float* t2 = hcur;
        hcur = hnxt;
        hnxt = t2;
    }

    head_kernel<<<NG, 128, 0, stream>>>(hcur, batch, fW1, fb1, fW2, fb2, out);
}